// Round 7
// baseline (1848.941 us; speedup 1.0000x reference)
//
#include <hip/hip_runtime.h>

typedef __attribute__((ext_vector_type(8))) __bf16 bf16x8;
typedef __attribute__((ext_vector_type(4))) float f32x4;

#define NH 32
#define DH 80
#define SEQ 1024
#define NB 4
#define NT 4096
#define HID 2560
#define NQKV 7680
#define SM_SCALE 0.11180339887498948f

static __device__ __forceinline__ unsigned short f2bf(float f) {
  unsigned u = __builtin_bit_cast(unsigned, f);
  u += 0x7fffu + ((u >> 16) & 1u);
  return (unsigned short)(u >> 16);
}
static __device__ __forceinline__ float bf2f(unsigned short s) {
  unsigned u = (unsigned)s << 16;
  return __builtin_bit_cast(float, u);
}

typedef __attribute__((address_space(1))) const unsigned int as1_uint;
typedef __attribute__((address_space(3))) unsigned int as3_uint;
static __device__ __forceinline__ void gload16(const void* g, void* l) {
  __builtin_amdgcn_global_load_lds((as1_uint*)g, (as3_uint*)l, 16, 0, 0);
}

// ---------------- fp32 -> bf16 convert (vectorized) ----------------
__global__ __launch_bounds__(256) void cvt_kernel(const float* __restrict__ in,
                                                  unsigned short* __restrict__ out,
                                                  int n4) {
  const float4* __restrict__ in4 = (const float4*)in;
  ushort4* __restrict__ out4 = (ushort4*)out;
  for (int i = blockIdx.x * blockDim.x + threadIdx.x; i < n4;
       i += gridDim.x * blockDim.x) {
    float4 v = in4[i];
    ushort4 o;
    o.x = f2bf(v.x);
    o.y = f2bf(v.y);
    o.z = f2bf(v.z);
    o.w = f2bf(v.w);
    out4[i] = o;
  }
}

// ---- 256x256 TLP-pipelined bf16 GEMM: C = A @ B^T + bias ----
// BK=32, 2-deep dbuf = 64 KiB LDS -> 2 blocks/CU (inter-block overlap hides
// the per-tile drain, m97 mechanism). 8 waves (2M x 4N), 1 barrier/tile.
// LDS [256][32] linear: fragment ds_read_b128 is natively conflict-free at
// 64B row stride (granule = (4*row+lg)&7 spreads 8 lanes/granule).
// EPI 0: q/k scatter [B][H][S][D]; V via in-LDS transpose -> coalesced
// [B][H][D][S] stores. EPI 1: fp32 C.
template <int EPI>
__global__ __launch_bounds__(512, 4) void gemm2b_kernel(
    const unsigned short* __restrict__ A, const unsigned short* __restrict__ Bm,
    const float* __restrict__ bias, unsigned short* __restrict__ Cq,
    unsigned short* __restrict__ Ck, unsigned short* __restrict__ Cv,
    float* __restrict__ Cf, int M, int N, int K) {
  __shared__ __align__(16) unsigned short As[2][8192];  // [buf][256 rows][32 k]
  __shared__ __align__(16) unsigned short Bs[2][8192];
  const int tid = threadIdx.x;
  const int lane = tid & 63, w = tid >> 6;
  const int wm = w >> 2, wn = w & 3;
  const int lr = lane & 15, lg = lane >> 4;

  // XCD-aware bijective block swizzle (nwg % 8 == 0 at both call sites)
  const int gx = gridDim.x;
  const int nwg = gx * gridDim.y;
  int bid = blockIdx.y * gx + blockIdx.x;
  bid = (bid & 7) * (nwg >> 3) + (bid >> 3);
  const int n0 = (bid % gx) * 256;
  const int m0 = (bid / gx) * 256;

  // Linear staging sources (no swizzle): chunk c covers LDS bytes
  // [c*8192, +8192) = rows c*128..+127; this thread's 16B at off=c*8192+tid*16.
  const unsigned short* asrc[2];
  const unsigned short* bsrc[2];
#pragma unroll
  for (int c = 0; c < 2; ++c) {
    const int off = c * 8192 + tid * 16;
    const int row = off >> 6, col = (off & 63) >> 1;
    asrc[c] = A + (size_t)(m0 + row) * K + col;
    bsrc[c] = Bm + (size_t)(n0 + row) * K + col;
  }

  const int NK = K >> 5;  // K-tiles of 32

#define STG(buf, kt)                                                     \
  {                                                                      \
    gload16(asrc[0] + (size_t)(kt)*32, (char*)&As[buf][0] + w * 1024);   \
    gload16(asrc[1] + (size_t)(kt)*32,                                   \
            (char*)&As[buf][0] + 8192 + w * 1024);                       \
    gload16(bsrc[0] + (size_t)(kt)*32, (char*)&Bs[buf][0] + w * 1024);   \
    gload16(bsrc[1] + (size_t)(kt)*32,                                   \
            (char*)&Bs[buf][0] + 8192 + w * 1024);                       \
  }
#define FRAG(basep, row) \
  (*(const bf16x8*)((const char*)(basep) + (row)*64 + lg * 16))

  f32x4 acc[8][4];
#pragma unroll
  for (int i = 0; i < 8; ++i)
#pragma unroll
    for (int j = 0; j < 4; ++j) acc[i][j] = (f32x4)0.0f;

  // prologue
  STG(0, 0);
  asm volatile("s_waitcnt vmcnt(0)" ::: "memory");
  __builtin_amdgcn_s_barrier();

  for (int t = 0; t < NK; ++t) {
    const int buf = t & 1, nb = buf ^ 1;
    const unsigned short* ab = &As[buf][0];
    const unsigned short* bb = &Bs[buf][0];
    const bool pf = (t + 1) < NK;
    if (pf) STG(nb, t + 1);  // issue early; lands in the idle buffer

    bf16x8 bfr[4], afr[4], afr2[4];
#pragma unroll
    for (int nf = 0; nf < 4; ++nf) bfr[nf] = FRAG(bb, wn * 64 + nf * 16 + lr);
#pragma unroll
    for (int mf = 0; mf < 4; ++mf) afr[mf] = FRAG(ab, wm * 128 + mf * 16 + lr);
#pragma unroll
    for (int mf = 0; mf < 4; ++mf)
#pragma unroll
      for (int nf = 0; nf < 4; ++nf)
        acc[mf][nf] =
            __builtin_amdgcn_mfma_f32_16x16x32_bf16(afr[mf], bfr[nf], acc[mf][nf], 0, 0, 0);
#pragma unroll
    for (int mf = 0; mf < 4; ++mf)
      afr2[mf] = FRAG(ab, wm * 128 + 64 + mf * 16 + lr);
#pragma unroll
    for (int mf = 0; mf < 4; ++mf)
#pragma unroll
      for (int nf = 0; nf < 4; ++nf)
        acc[mf + 4][nf] = __builtin_amdgcn_mfma_f32_16x16x32_bf16(
            afr2[mf], bfr[nf], acc[mf + 4][nf], 0, 0, 0);

    if (pf) asm volatile("s_waitcnt vmcnt(0)" ::: "memory");
    __builtin_amdgcn_s_barrier();
  }
#undef STG
#undef FRAG

  if (EPI == 0) {
    if (n0 >= 2 * HID) {
      // ---- V path: in-LDS transpose, then coalesced [B][H][D][S] stores ----
      unsigned short* scr = (w < 4) ? ((unsigned short*)&As[0][0] + w * 2176)
                                    : ((unsigned short*)&Bs[0][0] + (w - 4) * 2176);
      const int bb = (m0 + wm * 128) >> 10;
      const int ssb = (m0 + wm * 128) & 1023;
#pragma unroll
      for (int nf = 0; nf < 4; ++nf) {
        const int col0 = n0 - 2 * HID + wn * 64 + nf * 16;
        const int hh = col0 / DH;
        const int dd0 = col0 - hh * DH;
        const float bv = bias[2 * HID + col0 + lr];
        // write: scr[dd=lr][ss=mf*16+lg*4+r], stride 136 (conflict-free)
#pragma unroll
        for (int mf = 0; mf < 8; ++mf) {
          ushort4 p;
          p.x = f2bf(acc[mf][nf][0] + bv);
          p.y = f2bf(acc[mf][nf][1] + bv);
          p.z = f2bf(acc[mf][nf][2] + bv);
          p.w = f2bf(acc[mf][nf][3] + bv);
          *(ushort4*)&scr[lr * 136 + mf * 16 + lg * 4] = p;
        }
        // read rows (dd) and store 16B-contiguous along S
#pragma unroll
        for (int it = 0; it < 4; ++it) {
          const int dd = (lane >> 4) + it * 4;
          const int sl = (lane & 15) * 8;
          bf16x8 v = *(const bf16x8*)&scr[dd * 136 + sl];
          *(bf16x8*)(Cv + ((size_t)(bb * NH + hh) * DH + dd0 + dd) * SEQ + ssb + sl) = v;
        }
        asm volatile("s_waitcnt lgkmcnt(0)" ::: "memory");  // WAR vs next nf
      }
    } else {
      // ---- Q/K scatter path ----
#pragma unroll
      for (int nf = 0; nf < 4; ++nf) {
        const int col = n0 + wn * 64 + nf * 16 + lr;
        const int sec = col >= HID ? 1 : 0;
        const int rem = col - sec * HID;
        const int hh = rem / DH;
        const int dd = rem - hh * DH;
        unsigned short* dst = sec ? Ck : Cq;
        const float bv = bias[col];
#pragma unroll
        for (int mf = 0; mf < 8; ++mf) {
#pragma unroll
          for (int r = 0; r < 4; ++r) {
            const int tr = m0 + wm * 128 + mf * 16 + lg * 4 + r;
            const int bb2 = tr >> 10, ss = tr & 1023;
            dst[((size_t)(bb2 * NH + hh) * SEQ + ss) * DH + dd] =
                f2bf(acc[mf][nf][r] + bv);
          }
        }
      }
    }
  } else {
#pragma unroll
    for (int nf = 0; nf < 4; ++nf) {
      const int col = n0 + wn * 64 + nf * 16 + lr;
      const float bv = bias[col];
#pragma unroll
      for (int mf = 0; mf < 8; ++mf)
#pragma unroll
        for (int r = 0; r < 4; ++r) {
          const int row = m0 + wm * 128 + mf * 16 + lg * 4 + r;
          Cf[row * N + col] = acc[mf][nf][r] + bv;
        }
    }
  }
}

// ---------------- in-place partial rotary on Q and K ----------------
__global__ __launch_bounds__(256) void rope_kernel(unsigned short* __restrict__ Q,
                                                   unsigned short* __restrict__ K,
                                                   const float* __restrict__ cosb,
                                                   const float* __restrict__ sinb) {
  const int idx = blockIdx.x * 256 + threadIdx.x;  // B*H*S*16
  const int i = idx & 15;
  const int s = (idx >> 4) & 1023;
  const int bh = idx >> 14;
  const int b = bh >> 5;
  const int t = b * SEQ + s;
  const float c = cosb[t * 16 + i];
  const float sn = sinb[t * 16 + i];
  const int base = (bh * SEQ + s) * DH;
  float q1 = bf2f(Q[base + i]), q2 = bf2f(Q[base + 16 + i]);
  Q[base + i] = f2bf(q1 * c - q2 * sn);
  Q[base + 16 + i] = f2bf(q2 * c + q1 * sn);
  float k1 = bf2f(K[base + i]), k2 = bf2f(K[base + 16 + i]);
  K[base + i] = f2bf(k1 * c - k2 * sn);
  K[base + 16 + i] = f2bf(k2 * c + k1 * sn);
}

// ---------------- flash attention ----------------
// grid: (S/128, B*H). 512 threads = 8 waves; wave w owns q-rows
// [qt*128 + w*16, +16). V arrives already transposed ([B][H][D][S]).
__global__ __launch_bounds__(512) void attn_kernel(const unsigned short* __restrict__ Qb,
                                                   const unsigned short* __restrict__ Kb,
                                                   const unsigned short* __restrict__ Vg,
                                                   unsigned short* __restrict__ Ob) {
  __shared__ __align__(16) unsigned short Klds[64][104];  // D padded 80->96, stride 104
  __shared__ __align__(16) unsigned short Vt[80][72];     // V^T tile [d][k]
  __shared__ __align__(16) unsigned short Plds[8][16][72];
  const int tid = threadIdx.x;
  const int lane = tid & 63, w = tid >> 6;
  const int lr = lane & 15, lg = lane >> 4;
  const int koff = lg * 8;
  const int qt = blockIdx.x, bh = blockIdx.y;
  const int h = bh & 31;
  const int base = bh * (SEQ * DH);   // Q,K: [B][H][S][D]
  const int vbase = bh * (DH * SEQ);  // V:   [B][H][D][S]

  for (int e = tid; e < 64 * 16; e += 512) Klds[e >> 4][80 + (e & 15)] = 0;

  const int rowbase = qt * 128 + w * 16;
  const int qrow = rowbase + lr;
  bf16x8 qf[3];
#pragma unroll
  for (int c = 0; c < 3; ++c) {
    const int d = c * 32 + koff;
    if (d < DH)
      qf[c] = *(const bf16x8*)(Qb + base + qrow * DH + d);
    else
      qf[c] = (bf16x8)(__bf16)0.0f;
  }

  float m[4], l[4];
  f32x4 of[5];
#pragma unroll
  for (int r = 0; r < 4; ++r) {
    m[r] = -3.0e38f;
    l[r] = 0.0f;
  }
#pragma unroll
  for (int d = 0; d < 5; ++d) of[d] = (f32x4)0.0f;

  const int ktmax = 2 * qt + 1;
  for (int kt = 0; kt <= ktmax; ++kt) {
    __syncthreads();
    for (int e = tid; e < 640; e += 512) {
      const int r = e / 10, dc = (e - r * 10) * 8;
      *(bf16x8*)&Klds[r][dc] = *(const bf16x8*)(Kb + base + (kt * 64 + r) * DH + dc);
    }
    for (int e = tid; e < 640; e += 512) {
      const int d = e >> 3, sc = (e & 7) * 8;
      *(bf16x8*)&Vt[d][sc] = *(const bf16x8*)(Vg + vbase + d * SEQ + kt * 64 + sc);
    }
    __syncthreads();

    if (kt * 64 > rowbase + 15) continue;

    f32x4 sc[4];
#pragma unroll
    for (int cf = 0; cf < 4; ++cf) sc[cf] = (f32x4)0.0f;
#pragma unroll
    for (int c = 0; c < 3; ++c) {
#pragma unroll
      for (int cf = 0; cf < 4; ++cf) {
        bf16x8 kb = *(const bf16x8*)&Klds[cf * 16 + lr][c * 32 + koff];
        sc[cf] = __builtin_amdgcn_mfma_f32_16x16x32_bf16(qf[c], kb, sc[cf], 0, 0, 0);
      }
    }

    const int rowg = rowbase + lg * 4;
#pragma unroll
    for (int cf = 0; cf < 4; ++cf) {
      const int colg = kt * 64 + cf * 16 + lr;
#pragma unroll
      for (int r = 0; r < 4; ++r) {
        float v = sc[cf][r] * SM_SCALE;
        if (colg > rowg + r) v = -1.0e30f;
        sc[cf][r] = v;
      }
    }

    float al[4];
#pragma unroll
    for (int r = 0; r < 4; ++r) {
      float mx = fmaxf(fmaxf(sc[0][r], sc[1][r]), fmaxf(sc[2][r], sc[3][r]));
#pragma unroll
      for (int off = 1; off < 16; off <<= 1) mx = fmaxf(mx, __shfl_xor(mx, off, 64));
      const float mnew = fmaxf(m[r], mx);
      al[r] = __expf(m[r] - mnew);
      m[r] = mnew;
    }
    float ls[4] = {0.f, 0.f, 0.f, 0.f};
#pragma unroll
    for (int cf = 0; cf < 4; ++cf)
#pragma unroll
      for (int r = 0; r < 4; ++r) {
        const float p = __expf(sc[cf][r] - m[r]);
        sc[cf][r] = p;
        ls[r] += p;
      }
#pragma unroll
    for (int r = 0; r < 4; ++r) {
      float sv = ls[r];
#pragma unroll
      for (int off = 1; off < 16; off <<= 1) sv += __shfl_xor(sv, off, 64);
      l[r] = l[r] * al[r] + sv;
    }
#pragma unroll
    for (int d = 0; d < 5; ++d)
#pragma unroll
      for (int r = 0; r < 4; ++r) of[d][r] *= al[r];

#pragma unroll
    for (int cf = 0; cf < 4; ++cf)
#pragma unroll
      for (int r = 0; r < 4; ++r)
        Plds[w][lg * 4 + r][cf * 16 + lr] = f2bf(sc[cf][r]);

#pragma unroll
    for (int kc = 0; kc < 2; ++kc) {
      bf16x8 pa = *(const bf16x8*)&Plds[w][lr][kc * 32 + koff];
#pragma unroll
      for (int d = 0; d < 5; ++d) {
        bf16x8 vb = *(const bf16x8*)&Vt[d * 16 + lr][kc * 32 + koff];
        of[d] = __builtin_amdgcn_mfma_f32_16x16x32_bf16(pa, vb, of[d], 0, 0, 0);
      }
    }
  }

  const int t = (bh >> 5) * SEQ + rowbase + lg * 4;
#pragma unroll
  for (int r = 0; r < 4; ++r) {
    const float rl = 1.0f / l[r];
#pragma unroll
    for (int d = 0; d < 5; ++d)
      Ob[(t + r) * HID + h * DH + d * 16 + lr] = f2bf(of[d][r] * rl);
  }
}

// ---------------- launch ----------------
extern "C" void kernel_launch(void* const* d_in, const int* in_sizes, int n_in,
                              void* d_out, int out_size, void* d_ws, size_t ws_size,
                              hipStream_t stream) {
  const float* hs = (const float*)d_in[0];
  const float* cosb = (const float*)d_in[1];
  const float* sinb = (const float*)d_in[2];
  const float* w_qkv = (const float*)d_in[3];
  const float* b_qkv = (const float*)d_in[4];
  const float* w_dense = (const float*)d_in[5];
  const float* b_dense = (const float*)d_in[6];
  float* out = (float*)d_out;
  char* ws = (char*)d_ws;

  // workspace layout (total ~123.2 MB)
  unsigned short* hsb = (unsigned short*)(ws + 0);         // 21.0 MB (T*HID bf16)
  unsigned short* aob = (unsigned short*)(ws + 0);         // alias (attn out)
  unsigned short* wqb = (unsigned short*)(ws + 20971520);  // 39.3 MB
  unsigned short* wdb = (unsigned short*)(ws + 20971520);  // alias (after gemm1)
  unsigned short* Qb = (unsigned short*)(ws + 60293120);   // 21.0 MB
  unsigned short* Kb = (unsigned short*)(ws + 81264640);   // 21.0 MB
  unsigned short* Vb = (unsigned short*)(ws + 102236160);  // 21.0 MB ([B][H][D][S])

  cvt_kernel<<<2048, 256, 0, stream>>>(hs, hsb, (NT * HID) / 4);
  cvt_kernel<<<2048, 256, 0, stream>>>(w_qkv, wqb, (NQKV * HID) / 4);
  gemm2b_kernel<0><<<dim3(NQKV / 256, NT / 256), 512, 0, stream>>>(
      hsb, wqb, b_qkv, Qb, Kb, Vb, nullptr, NT, NQKV, HID);
  cvt_kernel<<<2048, 256, 0, stream>>>(w_dense, wdb, (HID * HID) / 4);
  rope_kernel<<<(NB * NH * SEQ * 16) / 256, 256, 0, stream>>>(Qb, Kb, cosb, sinb);
  attn_kernel<<<dim3(SEQ / 128, NB * NH), 512, 0, stream>>>(Qb, Kb, Vb, aob);
  gemm2b_kernel<1><<<dim3(HID / 256, NT / 256), 512, 0, stream>>>(
      aob, wdb, b_dense, nullptr, nullptr, nullptr, out, NT, HID, HID);
}

// Round 8
// 449.441 us; speedup vs baseline: 4.1139x; 4.1139x over previous
//
#include <hip/hip_runtime.h>

typedef __attribute__((ext_vector_type(8))) __bf16 bf16x8;
typedef __attribute__((ext_vector_type(4))) float f32x4;

#define NH 32
#define DH 80
#define SEQ 1024
#define NB 4
#define NT 4096
#define HID 2560
#define NQKV 7680
#define SM_SCALE 0.11180339887498948f

static __device__ __forceinline__ unsigned short f2bf(float f) {
  unsigned u = __builtin_bit_cast(unsigned, f);
  u += 0x7fffu + ((u >> 16) & 1u);
  return (unsigned short)(u >> 16);
}
static __device__ __forceinline__ float bf2f(unsigned short s) {
  unsigned u = (unsigned)s << 16;
  return __builtin_bit_cast(float, u);
}

typedef __attribute__((address_space(1))) const unsigned int as1_uint;
typedef __attribute__((address_space(3))) unsigned int as3_uint;
static __device__ __forceinline__ void gload16(const void* g, void* l) {
  __builtin_amdgcn_global_load_lds((as1_uint*)g, (as3_uint*)l, 16, 0, 0);
}

// ---------------- fp32 -> bf16 convert (vectorized) ----------------
__global__ __launch_bounds__(256) void cvt_kernel(const float* __restrict__ in,
                                                  unsigned short* __restrict__ out,
                                                  int n4) {
  const float4* __restrict__ in4 = (const float4*)in;
  ushort4* __restrict__ out4 = (ushort4*)out;
  for (int i = blockIdx.x * blockDim.x + threadIdx.x; i < n4;
       i += gridDim.x * blockDim.x) {
    float4 v = in4[i];
    ushort4 o;
    o.x = f2bf(v.x);
    o.y = f2bf(v.y);
    o.z = f2bf(v.z);
    o.w = f2bf(v.w);
    out4[i] = o;
  }
}

// ------------- 256x256-tile ring-pipelined bf16 GEMM: C = A @ B^T + bias ------
// ROUND-3 PROVEN STRUCTURE (207us QKV): 512 threads = 8 waves (2M x 4N);
// BK=32; 4-deep LDS ring; staging 3 tiles ahead via global_load_lds(16B) with
// pre-swizzled global source; counted vmcnt(8) at tile boundaries (never
// drains in steady state). LDS swizzle: byte ^= ((row>>1)&3)<<4.
// EPI 0: q/k scatter [B][H][S][D]; V via in-LDS transpose -> coalesced
// [B][H][D][S] stores. EPI 1: fp32 C.
template <int EPI>
__global__ __launch_bounds__(512, 2) void gemm256_kernel(
    const unsigned short* __restrict__ A, const unsigned short* __restrict__ Bm,
    const float* __restrict__ bias, unsigned short* __restrict__ Cq,
    unsigned short* __restrict__ Ck, unsigned short* __restrict__ Cv,
    float* __restrict__ Cf, int M, int N, int K) {
  __shared__ __align__(16) unsigned short As[4][8192];  // 4 x [256 rows][32 k]
  __shared__ __align__(16) unsigned short Bs[4][8192];
  const int tid = threadIdx.x;
  const int lane = tid & 63, w = tid >> 6;
  const int wm = w >> 2, wn = w & 3;
  const int lr = lane & 15, lg = lane >> 4;

  // XCD-aware bijective block swizzle (nwg % 8 == 0 at both call sites)
  const int gx = gridDim.x;
  const int nwg = gx * gridDim.y;
  int bid = blockIdx.y * gx + blockIdx.x;
  bid = (bid & 7) * (nwg >> 3) + (bid >> 3);
  const int n0 = (bid % gx) * 256;
  const int m0 = (bid / gx) * 256;

  // Per-lane pre-swizzled global sources. Chunk ch covers LDS bytes
  // [ch*8192, +8192) (rows 128*ch..+127); this thread's 16B lands at
  // off = ch*8192 + tid*16; it carries the element whose unswizzled offset
  // is u = off ^ ((off>>7)&3)<<4.
  const unsigned short* asrc[2];
  const unsigned short* bsrc[2];
#pragma unroll
  for (int i = 0; i < 2; ++i) {
    const int off = i * 8192 + tid * 16;
    const int u = off ^ (((off >> 7) & 3) << 4);
    const int row = u >> 6, col = (u & 63) >> 1;
    asrc[i] = A + (size_t)(m0 + row) * K + col;
    bsrc[i] = Bm + (size_t)(n0 + row) * K + col;
  }

  const int NTl = K >> 5;  // K-tiles of 32

#define STAGE_A(buf, kt, ch) \
  gload16(asrc[ch] + (kt) * 32, (char*)&As[buf][0] + (ch) * 8192 + w * 1024)
#define STAGE_B(buf, kt, ch) \
  gload16(bsrc[ch] + (kt) * 32, (char*)&Bs[buf][0] + (ch) * 8192 + w * 1024)

  // prologue: stage tiles 0,1,2 into ring slots 0,1,2 (12 gloads in flight)
  STAGE_A(0, 0, 0); STAGE_A(0, 0, 1); STAGE_B(0, 0, 0); STAGE_B(0, 0, 1);
  STAGE_A(1, 1, 0); STAGE_A(1, 1, 1); STAGE_B(1, 1, 0); STAGE_B(1, 1, 1);
  STAGE_A(2, 2, 0); STAGE_A(2, 2, 1); STAGE_B(2, 2, 0); STAGE_B(2, 2, 1);

  f32x4 acc[8][4];
#pragma unroll
  for (int i = 0; i < 8; ++i)
#pragma unroll
    for (int j = 0; j < 4; ++j) acc[i][j] = (f32x4)0.0f;

  for (int t = 0; t < NTl; ++t) {
    const int c = t & 3;
    const char* ap = (const char*)&As[c][0];
    const char* bp = (const char*)&Bs[c][0];
    // tile-start: own loads for tile t landed (2 later tiles' 8 loads stay
    // in flight); only the last two tiles drain 4 -> 0.
    if (t + 2 < NTl)
      asm volatile("s_waitcnt vmcnt(8)" ::: "memory");
    else if (t + 1 < NTl)
      asm volatile("s_waitcnt vmcnt(4)" ::: "memory");
    else
      asm volatile("s_waitcnt vmcnt(0)" ::: "memory");
    __builtin_amdgcn_s_barrier();

    bf16x8 breg[4], areg[4], areg2[4];
    // ---- phase 0: read B(all) + A(mf0-3); prefetch A-chunks of tile t+3 ----
#pragma unroll
    for (int nf = 0; nf < 4; ++nf) {
      const int row = wn * 64 + nf * 16 + lr;
      const int ub = row * 64 + lg * 16;
      breg[nf] = *(const bf16x8*)(bp + (ub ^ (((row >> 1) & 3) << 4)));
    }
#pragma unroll
    for (int mf = 0; mf < 4; ++mf) {
      const int row = wm * 128 + mf * 16 + lr;
      const int ub = row * 64 + lg * 16;
      areg[mf] = *(const bf16x8*)(ap + (ub ^ (((row >> 1) & 3) << 4)));
    }
    if (t + 3 < NTl) {
      STAGE_A((t + 3) & 3, t + 3, 0);
      STAGE_A((t + 3) & 3, t + 3, 1);
    }
    __builtin_amdgcn_s_barrier();
    __builtin_amdgcn_s_setprio(1);
#pragma unroll
    for (int mf = 0; mf < 4; ++mf)
#pragma unroll
      for (int nf = 0; nf < 4; ++nf)
        acc[mf][nf] = __builtin_amdgcn_mfma_f32_16x16x32_bf16(areg[mf], breg[nf],
                                                              acc[mf][nf], 0, 0, 0);
    __builtin_amdgcn_s_setprio(0);
    // ---- phase 1: read A(mf4-7); prefetch B-chunks of tile t+3 ----
#pragma unroll
    for (int mf = 0; mf < 4; ++mf) {
      const int row = wm * 128 + (mf + 4) * 16 + lr;
      const int ub = row * 64 + lg * 16;
      areg2[mf] = *(const bf16x8*)(ap + (ub ^ (((row >> 1) & 3) << 4)));
    }
    if (t + 3 < NTl) {
      STAGE_B((t + 3) & 3, t + 3, 0);
      STAGE_B((t + 3) & 3, t + 3, 1);
    }
    __builtin_amdgcn_s_barrier();
    __builtin_amdgcn_s_setprio(1);
#pragma unroll
    for (int mf = 0; mf < 4; ++mf)
#pragma unroll
      for (int nf = 0; nf < 4; ++nf)
        acc[mf + 4][nf] = __builtin_amdgcn_mfma_f32_16x16x32_bf16(
            areg2[mf], breg[nf], acc[mf + 4][nf], 0, 0, 0);
    __builtin_amdgcn_s_setprio(0);
  }
#undef STAGE_A
#undef STAGE_B

  if (EPI == 0) {
    if (n0 >= 2 * HID) {
      // ---- V path: in-LDS transpose, then coalesced [B][H][D][S] stores ----
      // per-wave scratch region in As (done with K-loop; all waves past the
      // final barrier). 16 rows (dd) x 128 cols (ss), stride 136.
      unsigned short* scr = (unsigned short*)&As[0][0] + w * 2176;
      const int bb = (m0 + wm * 128) >> 10;
      const int ssb = (m0 + wm * 128) & 1023;
#pragma unroll
      for (int nf = 0; nf < 4; ++nf) {
        const int col0 = n0 - 2 * HID + wn * 64 + nf * 16;
        const int hh = col0 / DH;
        const int dd0 = col0 - hh * DH;
        const float bv = bias[2 * HID + col0 + lr];
        // write: scr[dd=lr][ss=mf*16+lg*4+r]
#pragma unroll
        for (int mf = 0; mf < 8; ++mf) {
          ushort4 p;
          p.x = f2bf(acc[mf][nf][0] + bv);
          p.y = f2bf(acc[mf][nf][1] + bv);
          p.z = f2bf(acc[mf][nf][2] + bv);
          p.w = f2bf(acc[mf][nf][3] + bv);
          *(ushort4*)&scr[lr * 136 + mf * 16 + lg * 4] = p;
        }
        // read rows (dd) and store 16B-contiguous along S (256B runs)
#pragma unroll
        for (int it = 0; it < 4; ++it) {
          const int dd = (lane >> 4) + it * 4;
          const int sl = (lane & 15) * 8;
          bf16x8 v = *(const bf16x8*)&scr[dd * 136 + sl];
          *(bf16x8*)(Cv + ((size_t)(bb * NH + hh) * DH + dd0 + dd) * SEQ + ssb + sl) = v;
        }
        asm volatile("s_waitcnt lgkmcnt(0)" ::: "memory");  // WAR vs next nf
      }
    } else {
      // ---- Q/K scatter path ----
#pragma unroll
      for (int nf = 0; nf < 4; ++nf) {
        const int col = n0 + wn * 64 + nf * 16 + lr;
        const int sec = col >= HID ? 1 : 0;
        const int rem = col - sec * HID;
        const int hh = rem / DH;
        const int dd = rem - hh * DH;
        unsigned short* dst = sec ? Ck : Cq;
        const float bv = bias[col];
#pragma unroll
        for (int mf = 0; mf < 8; ++mf) {
#pragma unroll
          for (int r = 0; r < 4; ++r) {
            const int tr = m0 + wm * 128 + mf * 16 + lg * 4 + r;
            const int bb2 = tr >> 10, ss = tr & 1023;
            dst[((size_t)(bb2 * NH + hh) * SEQ + ss) * DH + dd] =
                f2bf(acc[mf][nf][r] + bv);
          }
        }
      }
    }
  } else {
#pragma unroll
    for (int nf = 0; nf < 4; ++nf) {
      const int col = n0 + wn * 64 + nf * 16 + lr;
      const float bv = bias[col];
#pragma unroll
      for (int mf = 0; mf < 8; ++mf)
#pragma unroll
        for (int r = 0; r < 4; ++r) {
          const int row = m0 + wm * 128 + mf * 16 + lg * 4 + r;
          Cf[row * N + col] = acc[mf][nf][r] + bv;
        }
    }
  }
}

// ---------------- in-place partial rotary on Q and K ----------------
__global__ __launch_bounds__(256) void rope_kernel(unsigned short* __restrict__ Q,
                                                   unsigned short* __restrict__ K,
                                                   const float* __restrict__ cosb,
                                                   const float* __restrict__ sinb) {
  const int idx = blockIdx.x * 256 + threadIdx.x;  // B*H*S*16
  const int i = idx & 15;
  const int s = (idx >> 4) & 1023;
  const int bh = idx >> 14;
  const int b = bh >> 5;
  const int t = b * SEQ + s;
  const float c = cosb[t * 16 + i];
  const float sn = sinb[t * 16 + i];
  const int base = (bh * SEQ + s) * DH;
  float q1 = bf2f(Q[base + i]), q2 = bf2f(Q[base + 16 + i]);
  Q[base + i] = f2bf(q1 * c - q2 * sn);
  Q[base + 16 + i] = f2bf(q2 * c + q1 * sn);
  float k1 = bf2f(K[base + i]), k2 = bf2f(K[base + 16 + i]);
  K[base + i] = f2bf(k1 * c - k2 * sn);
  K[base + 16 + i] = f2bf(k2 * c + k1 * sn);
}

// ---------------- flash attention ----------------
// grid: (S/128, B*H). 512 threads = 8 waves; wave w owns q-rows
// [qt*128 + w*16, +16). V arrives already transposed ([B][H][D][S]).
__global__ __launch_bounds__(512) void attn_kernel(const unsigned short* __restrict__ Qb,
                                                   const unsigned short* __restrict__ Kb,
                                                   const unsigned short* __restrict__ Vg,
                                                   unsigned short* __restrict__ Ob) {
  __shared__ __align__(16) unsigned short Klds[64][104];  // D padded 80->96, stride 104
  __shared__ __align__(16) unsigned short Vt[80][72];     // V^T tile [d][k]
  __shared__ __align__(16) unsigned short Plds[8][16][72];
  const int tid = threadIdx.x;
  const int lane = tid & 63, w = tid >> 6;
  const int lr = lane & 15, lg = lane >> 4;
  const int koff = lg * 8;
  const int qt = blockIdx.x, bh = blockIdx.y;
  const int h = bh & 31;
  const int base = bh * (SEQ * DH);   // Q,K: [B][H][S][D]
  const int vbase = bh * (DH * SEQ);  // V:   [B][H][D][S]

  for (int e = tid; e < 64 * 16; e += 512) Klds[e >> 4][80 + (e & 15)] = 0;

  const int rowbase = qt * 128 + w * 16;
  const int qrow = rowbase + lr;
  bf16x8 qf[3];
#pragma unroll
  for (int c = 0; c < 3; ++c) {
    const int d = c * 32 + koff;
    if (d < DH)
      qf[c] = *(const bf16x8*)(Qb + base + qrow * DH + d);
    else
      qf[c] = (bf16x8)(__bf16)0.0f;
  }

  float m[4], l[4];
  f32x4 of[5];
#pragma unroll
  for (int r = 0; r < 4; ++r) {
    m[r] = -3.0e38f;
    l[r] = 0.0f;
  }
#pragma unroll
  for (int d = 0; d < 5; ++d) of[d] = (f32x4)0.0f;

  const int ktmax = 2 * qt + 1;
  for (int kt = 0; kt <= ktmax; ++kt) {
    __syncthreads();
    for (int e = tid; e < 640; e += 512) {
      const int r = e / 10, dc = (e - r * 10) * 8;
      *(bf16x8*)&Klds[r][dc] = *(const bf16x8*)(Kb + base + (kt * 64 + r) * DH + dc);
    }
    for (int e = tid; e < 640; e += 512) {
      const int d = e >> 3, sc = (e & 7) * 8;
      *(bf16x8*)&Vt[d][sc] = *(const bf16x8*)(Vg + vbase + d * SEQ + kt * 64 + sc);
    }
    __syncthreads();

    if (kt * 64 > rowbase + 15) continue;

    f32x4 sc[4];
#pragma unroll
    for (int cf = 0; cf < 4; ++cf) sc[cf] = (f32x4)0.0f;
#pragma unroll
    for (int c = 0; c < 3; ++c) {
#pragma unroll
      for (int cf = 0; cf < 4; ++cf) {
        bf16x8 kb = *(const bf16x8*)&Klds[cf * 16 + lr][c * 32 + koff];
        sc[cf] = __builtin_amdgcn_mfma_f32_16x16x32_bf16(qf[c], kb, sc[cf], 0, 0, 0);
      }
    }

    const int rowg = rowbase + lg * 4;
#pragma unroll
    for (int cf = 0; cf < 4; ++cf) {
      const int colg = kt * 64 + cf * 16 + lr;
#pragma unroll
      for (int r = 0; r < 4; ++r) {
        float v = sc[cf][r] * SM_SCALE;
        if (colg > rowg + r) v = -1.0e30f;
        sc[cf][r] = v;
      }
    }

    float al[4];
#pragma unroll
    for (int r = 0; r < 4; ++r) {
      float mx = fmaxf(fmaxf(sc[0][r], sc[1][r]), fmaxf(sc[2][r], sc[3][r]));
#pragma unroll
      for (int off = 1; off < 16; off <<= 1) mx = fmaxf(mx, __shfl_xor(mx, off, 64));
      const float mnew = fmaxf(m[r], mx);
      al[r] = __expf(m[r] - mnew);
      m[r] = mnew;
    }
    float ls[4] = {0.f, 0.f, 0.f, 0.f};
#pragma unroll
    for (int cf = 0; cf < 4; ++cf)
#pragma unroll
      for (int r = 0; r < 4; ++r) {
        const float p = __expf(sc[cf][r] - m[r]);
        sc[cf][r] = p;
        ls[r] += p;
      }
#pragma unroll
    for (int r = 0; r < 4; ++r) {
      float sv = ls[r];
#pragma unroll
      for (int off = 1; off < 16; off <<= 1) sv += __shfl_xor(sv, off, 64);
      l[r] = l[r] * al[r] + sv;
    }
#pragma unroll
    for (int d = 0; d < 5; ++d)
#pragma unroll
      for (int r = 0; r < 4; ++r) of[d][r] *= al[r];

#pragma unroll
    for (int cf = 0; cf < 4; ++cf)
#pragma unroll
      for (int r = 0; r < 4; ++r)
        Plds[w][lg * 4 + r][cf * 16 + lr] = f2bf(sc[cf][r]);

#pragma unroll
    for (int kc = 0; kc < 2; ++kc) {
      bf16x8 pa = *(const bf16x8*)&Plds[w][lr][kc * 32 + koff];
#pragma unroll
      for (int d = 0; d < 5; ++d) {
        bf16x8 vb = *(const bf16x8*)&Vt[d * 16 + lr][kc * 32 + koff];
        of[d] = __builtin_amdgcn_mfma_f32_16x16x32_bf16(pa, vb, of[d], 0, 0, 0);
      }
    }
  }

  const int t = (bh >> 5) * SEQ + rowbase + lg * 4;
#pragma unroll
  for (int r = 0; r < 4; ++r) {
    const float rl = 1.0f / l[r];
#pragma unroll
    for (int d = 0; d < 5; ++d)
      Ob[(t + r) * HID + h * DH + d * 16 + lr] = f2bf(of[d][r] * rl);
  }
}

// ---------------- launch ----------------
extern "C" void kernel_launch(void* const* d_in, const int* in_sizes, int n_in,
                              void* d_out, int out_size, void* d_ws, size_t ws_size,
                              hipStream_t stream) {
  const float* hs = (const float*)d_in[0];
  const float* cosb = (const float*)d_in[1];
  const float* sinb = (const float*)d_in[2];
  const float* w_qkv = (const float*)d_in[3];
  const float* b_qkv = (const float*)d_in[4];
  const float* w_dense = (const float*)d_in[5];
  const float* b_dense = (const float*)d_in[6];
  float* out = (float*)d_out;
  char* ws = (char*)d_ws;

  // workspace layout (total ~123.2 MB)
  unsigned short* hsb = (unsigned short*)(ws + 0);         // 21.0 MB (T*HID bf16)
  unsigned short* aob = (unsigned short*)(ws + 0);         // alias (attn out)
  unsigned short* wqb = (unsigned short*)(ws + 20971520);  // 39.3 MB
  unsigned short* wdb = (unsigned short*)(ws + 20971520);  // alias (after gemm1)
  unsigned short* Qb = (unsigned short*)(ws + 60293120);   // 21.0 MB
  unsigned short* Kb = (unsigned short*)(ws + 81264640);   // 21.0 MB
  unsigned short* Vb = (unsigned short*)(ws + 102236160);  // 21.0 MB ([B][H][D][S])

  cvt_kernel<<<2048, 256, 0, stream>>>(hs, hsb, (NT * HID) / 4);
  cvt_kernel<<<2048, 256, 0, stream>>>(w_qkv, wqb, (NQKV * HID) / 4);
  gemm256_kernel<0><<<dim3(NQKV / 256, NT / 256), 512, 0, stream>>>(
      hsb, wqb, b_qkv, Qb, Kb, Vb, nullptr, NT, NQKV, HID);
  cvt_kernel<<<2048, 256, 0, stream>>>(w_dense, wdb, (HID * HID) / 4);
  rope_kernel<<<(NB * NH * SEQ * 16) / 256, 256, 0, stream>>>(Qb, Kb, cosb, sinb);
  attn_kernel<<<dim3(SEQ / 128, NB * NH), 512, 0, stream>>>(Qb, Kb, Vb, aob);
  gemm256_kernel<1><<<dim3(HID / 256, NT / 256), 512, 0, stream>>>(
      aob, wdb, b_dense, nullptr, nullptr, nullptr, out, NT, HID, HID);
}

// Round 9
// 441.719 us; speedup vs baseline: 4.1858x; 1.0175x over previous
//
#include <hip/hip_runtime.h>

typedef __attribute__((ext_vector_type(8))) __bf16 bf16x8;
typedef __attribute__((ext_vector_type(4))) float f32x4;

#define NH 32
#define DH 80
#define SEQ 1024
#define NB 4
#define NT 4096
#define HID 2560
#define NQKV 7680
#define SM_SCALE 0.11180339887498948f

static __device__ __forceinline__ unsigned short f2bf(float f) {
  unsigned u = __builtin_bit_cast(unsigned, f);
  u += 0x7fffu + ((u >> 16) & 1u);
  return (unsigned short)(u >> 16);
}
static __device__ __forceinline__ float bf2f(unsigned short s) {
  unsigned u = (unsigned)s << 16;
  return __builtin_bit_cast(float, u);
}

typedef __attribute__((address_space(1))) const unsigned int as1_uint;
typedef __attribute__((address_space(3))) unsigned int as3_uint;
static __device__ __forceinline__ void gload16(const void* g, void* l) {
  __builtin_amdgcn_global_load_lds((as1_uint*)g, (as3_uint*)l, 16, 0, 0);
}

// ---------------- fp32 -> bf16 convert (vectorized) ----------------
__global__ __launch_bounds__(256) void cvt_kernel(const float* __restrict__ in,
                                                  unsigned short* __restrict__ out,
                                                  int n4) {
  const float4* __restrict__ in4 = (const float4*)in;
  ushort4* __restrict__ out4 = (ushort4*)out;
  for (int i = blockIdx.x * blockDim.x + threadIdx.x; i < n4;
       i += gridDim.x * blockDim.x) {
    float4 v = in4[i];
    ushort4 o;
    o.x = f2bf(v.x);
    o.y = f2bf(v.y);
    o.z = f2bf(v.z);
    o.w = f2bf(v.w);
    out4[i] = o;
  }
}

// ------------- 256x256 8-phase pipelined bf16 GEMM: C = A @ B^T + bias -------
// m201-faithful schedule: BK=64, 2 K-tiles/iter, 8 phases (quadrant of 16 MFMA
// each), LDS [buf][half][128][64] x(A,B) = 128 KiB, (row&7)<<4 XOR swizzle via
// pre-swizzled global source (linear DMA dest). 1 half-tile staged per phase,
// placed one phase after the last read of the buffer it overwrites (post-MFMA
// barrier guarantees reads complete). Waits: uniform vmcnt(4) at ph4/ph8 only
// (never drains in steady state); vmcnt(0) only at the last iter's ph4.
// Wave layout: 8 waves 2Mx4N; wave reads only A-half[wm] and B-half[wn>>1].
// EPI 0: q/k scatter [B][H][S][D]; V via in-LDS transpose -> [B][H][D][S].
// EPI 1: fp32 C.
template <int EPI>
__global__ __launch_bounds__(512, 2) void gemm8p_kernel(
    const unsigned short* __restrict__ A, const unsigned short* __restrict__ Bm,
    const float* __restrict__ bias, unsigned short* __restrict__ Cq,
    unsigned short* __restrict__ Ck, unsigned short* __restrict__ Cv,
    float* __restrict__ Cf, int M, int N, int K) {
  __shared__ __align__(16) unsigned short AL[2][2][8192];  // [buf][half][128*64]
  __shared__ __align__(16) unsigned short BL[2][2][8192];
  const int tid = threadIdx.x;
  const int lane = tid & 63, w = tid >> 6;
  const int wm = w >> 2, wn = w & 3;
  const int lr = lane & 15, lg = lane >> 4;
  const int bhh = wn >> 1;         // B half this wave reads
  const int brow = (wn & 1) * 64;  // B local row base

  // XCD-aware bijective block swizzle (nwg % 8 == 0 at both call sites)
  const int gx = gridDim.x;
  const int nwg = gx * gridDim.y;
  int bid = blockIdx.y * gx + blockIdx.x;
  bid = (bid & 7) * (nwg >> 3) + (bid >> 3);
  const int n0 = (bid % gx) * 256;
  const int m0 = (bid / gx) * 256;

  // Pre-swizzled per-lane staging sources for each (half, chunk).
  const unsigned short* asrc[2][2];
  const unsigned short* bsrc[2][2];
#pragma unroll
  for (int h = 0; h < 2; ++h)
#pragma unroll
    for (int j = 0; j < 2; ++j) {
      const int off = j * 8192 + tid * 16;
      const int u = off ^ (((off >> 7) & 7) << 4);
      const int row = u >> 7, col = (u & 127) >> 1;
      asrc[h][j] = A + (size_t)(m0 + h * 128 + row) * K + col;
      bsrc[h][j] = Bm + (size_t)(n0 + h * 128 + row) * K + col;
    }

  const int NK = K >> 6, NIT = NK >> 1;

#define SA(buf, h, kt)                                                     \
  do {                                                                     \
    gload16(asrc[h][0] + (size_t)(kt) * 64,                                \
            (char*)&AL[buf][h][0] + w * 1024);                             \
    gload16(asrc[h][1] + (size_t)(kt) * 64,                                \
            (char*)&AL[buf][h][0] + 8192 + w * 1024);                      \
  } while (0)
#define SB(buf, h, kt)                                                     \
  do {                                                                     \
    gload16(bsrc[h][0] + (size_t)(kt) * 64,                                \
            (char*)&BL[buf][h][0] + w * 1024);                             \
    gload16(bsrc[h][1] + (size_t)(kt) * 64,                                \
            (char*)&BL[buf][h][0] + 8192 + w * 1024);                      \
  } while (0)
// Swizzled fragment reads (within this wave's half).
#define FA(buf, lrow, ks)                                                  \
  (*(const bf16x8*)((const char*)&AL[buf][wm][0] +                         \
                    (((lrow) * 128 + (ks) * 64 + lg * 16) ^                \
                     (((lrow) & 7) << 4))))
#define FB(buf, lrow, ks)                                                  \
  (*(const bf16x8*)((const char*)&BL[buf][bhh][0] +                        \
                    (((lrow) * 128 + (ks) * 64 + lg * 16) ^                \
                     (((lrow) & 7) << 4))))
// One phase's MFMA cluster: quadrant (m-base AIDX, n-base NBASE) x K=64.
#define PH_MFMA(AIDX, NBASE, BREG)                                         \
  __builtin_amdgcn_s_barrier();                                            \
  __builtin_amdgcn_s_setprio(1);                                           \
  _Pragma("unroll") for (int mf = 0; mf < 4; ++mf)                         \
      _Pragma("unroll") for (int nf = 0; nf < 2; ++nf) {                   \
    acc[AIDX + mf][NBASE + nf] = __builtin_amdgcn_mfma_f32_16x16x32_bf16(  \
        af[mf * 2 + 0], BREG[nf * 2 + 0], acc[AIDX + mf][NBASE + nf], 0, 0, 0); \
    acc[AIDX + mf][NBASE + nf] = __builtin_amdgcn_mfma_f32_16x16x32_bf16(  \
        af[mf * 2 + 1], BREG[nf * 2 + 1], acc[AIDX + mf][NBASE + nf], 0, 0, 0); \
  }                                                                        \
  __builtin_amdgcn_s_setprio(0);

  f32x4 acc[8][4];
#pragma unroll
  for (int i = 0; i < 8; ++i)
#pragma unroll
    for (int j = 0; j < 4; ++j) acc[i][j] = (f32x4)0.0f;

  // prologue: tile0 all 4 halves + tile1 {B0,A0}; wait first 4 HTs; barrier
  SB(0, 0, 0); SA(0, 0, 0); SB(0, 1, 0); SA(0, 1, 0);
  SB(1, 0, 1); SA(1, 0, 1);
  asm volatile("s_waitcnt vmcnt(4)" ::: "memory");
  __builtin_amdgcn_s_barrier();

  bf16x8 af[8], bl[4], bhf[4];

  for (int i = 0; i < NIT; ++i) {
    const int t1 = 2 * i + 1, t2 = 2 * i + 2, t3 = 2 * i + 3;
    const bool p2 = t2 < NK, p3 = t3 < NK;

    // ---------- tile 2i (buf 0) ----------
    // ph1: quad(m-lo, n-lo); stage B1(t1)
#pragma unroll
    for (int mf = 0; mf < 4; ++mf) {
      af[mf * 2 + 0] = FA(0, mf * 16 + lr, 0);
      af[mf * 2 + 1] = FA(0, mf * 16 + lr, 1);
    }
#pragma unroll
    for (int nf = 0; nf < 2; ++nf) {
      bl[nf * 2 + 0] = FB(0, brow + nf * 16 + lr, 0);
      bl[nf * 2 + 1] = FB(0, brow + nf * 16 + lr, 1);
    }
    SB(1, 1, t1);
    PH_MFMA(0, 0, bl)
    __builtin_amdgcn_s_barrier();
    // ph2: quad(m-lo, n-hi); stage A1(t1)
#pragma unroll
    for (int nf = 0; nf < 2; ++nf) {
      bhf[nf * 2 + 0] = FB(0, brow + (nf + 2) * 16 + lr, 0);
      bhf[nf * 2 + 1] = FB(0, brow + (nf + 2) * 16 + lr, 1);
    }
    SA(1, 1, t1);
    PH_MFMA(0, 2, bhf)
    __builtin_amdgcn_s_barrier();
    // ph3: quad(m-hi, n-lo); stage B0(t2)
#pragma unroll
    for (int mf = 0; mf < 4; ++mf) {
      af[mf * 2 + 0] = FA(0, 64 + mf * 16 + lr, 0);
      af[mf * 2 + 1] = FA(0, 64 + mf * 16 + lr, 1);
    }
    if (p2) SB(0, 0, t2);
    PH_MFMA(4, 0, bl)
    __builtin_amdgcn_s_barrier();
    // ph4: quad(m-hi, n-hi); stage A0(t2); counted wait
    if (p2) SA(0, 0, t2);
    PH_MFMA(4, 2, bhf)
    if (i + 1 < NIT)
      asm volatile("s_waitcnt vmcnt(4)" ::: "memory");
    else
      asm volatile("s_waitcnt vmcnt(0)" ::: "memory");
    __builtin_amdgcn_s_barrier();

    // ---------- tile 2i+1 (buf 1) ----------
    // ph5: quad(m-lo, n-lo); stage B1(t2)
#pragma unroll
    for (int mf = 0; mf < 4; ++mf) {
      af[mf * 2 + 0] = FA(1, mf * 16 + lr, 0);
      af[mf * 2 + 1] = FA(1, mf * 16 + lr, 1);
    }
#pragma unroll
    for (int nf = 0; nf < 2; ++nf) {
      bl[nf * 2 + 0] = FB(1, brow + nf * 16 + lr, 0);
      bl[nf * 2 + 1] = FB(1, brow + nf * 16 + lr, 1);
    }
    if (p2) SB(0, 1, t2);
    PH_MFMA(0, 0, bl)
    __builtin_amdgcn_s_barrier();
    // ph6: quad(m-lo, n-hi); stage A1(t2)
#pragma unroll
    for (int nf = 0; nf < 2; ++nf) {
      bhf[nf * 2 + 0] = FB(1, brow + (nf + 2) * 16 + lr, 0);
      bhf[nf * 2 + 1] = FB(1, brow + (nf + 2) * 16 + lr, 1);
    }
    if (p2) SA(0, 1, t2);
    PH_MFMA(0, 2, bhf)
    __builtin_amdgcn_s_barrier();
    // ph7: quad(m-hi, n-lo); stage B0(t3)
#pragma unroll
    for (int mf = 0; mf < 4; ++mf) {
      af[mf * 2 + 0] = FA(1, 64 + mf * 16 + lr, 0);
      af[mf * 2 + 1] = FA(1, 64 + mf * 16 + lr, 1);
    }
    if (p3) SB(1, 0, t3);
    PH_MFMA(4, 0, bl)
    __builtin_amdgcn_s_barrier();
    // ph8: quad(m-hi, n-hi); stage A0(t3); counted wait
    if (p3) SA(1, 0, t3);
    PH_MFMA(4, 2, bhf)
    if (i + 1 < NIT) asm volatile("s_waitcnt vmcnt(4)" ::: "memory");
    __builtin_amdgcn_s_barrier();
  }
#undef SA
#undef SB
#undef FA
#undef FB
#undef PH_MFMA

  if (EPI == 0) {
    if (n0 >= 2 * HID) {
      // ---- V path: in-LDS transpose, then coalesced [B][H][D][S] stores ----
      unsigned short* scr = (unsigned short*)&AL[0][0][0] + w * 2176;
      const int bb = (m0 + wm * 128) >> 10;
      const int ssb = (m0 + wm * 128) & 1023;
#pragma unroll
      for (int nf = 0; nf < 4; ++nf) {
        const int col0 = n0 - 2 * HID + wn * 64 + nf * 16;
        const int hh = col0 / DH;
        const int dd0 = col0 - hh * DH;
        const float bv = bias[2 * HID + col0 + lr];
#pragma unroll
        for (int mf = 0; mf < 8; ++mf) {
          ushort4 p;
          p.x = f2bf(acc[mf][nf][0] + bv);
          p.y = f2bf(acc[mf][nf][1] + bv);
          p.z = f2bf(acc[mf][nf][2] + bv);
          p.w = f2bf(acc[mf][nf][3] + bv);
          *(ushort4*)&scr[lr * 136 + mf * 16 + lg * 4] = p;
        }
#pragma unroll
        for (int it = 0; it < 4; ++it) {
          const int dd = (lane >> 4) + it * 4;
          const int sl = (lane & 15) * 8;
          bf16x8 v = *(const bf16x8*)&scr[dd * 136 + sl];
          *(bf16x8*)(Cv + ((size_t)(bb * NH + hh) * DH + dd0 + dd) * SEQ + ssb + sl) = v;
        }
        asm volatile("s_waitcnt lgkmcnt(0)" ::: "memory");  // WAR vs next nf
      }
    } else {
      // ---- Q/K scatter path ----
#pragma unroll
      for (int nf = 0; nf < 4; ++nf) {
        const int col = n0 + wn * 64 + nf * 16 + lr;
        const int sec = col >= HID ? 1 : 0;
        const int rem = col - sec * HID;
        const int hh = rem / DH;
        const int dd = rem - hh * DH;
        unsigned short* dst = sec ? Ck : Cq;
        const float bv = bias[col];
#pragma unroll
        for (int mf = 0; mf < 8; ++mf) {
#pragma unroll
          for (int r = 0; r < 4; ++r) {
            const int tr = m0 + wm * 128 + mf * 16 + lg * 4 + r;
            const int bb2 = tr >> 10, ss = tr & 1023;
            dst[((size_t)(bb2 * NH + hh) * SEQ + ss) * DH + dd] =
                f2bf(acc[mf][nf][r] + bv);
          }
        }
      }
    }
  } else {
#pragma unroll
    for (int nf = 0; nf < 4; ++nf) {
      const int col = n0 + wn * 64 + nf * 16 + lr;
      const float bv = bias[col];
#pragma unroll
      for (int mf = 0; mf < 8; ++mf)
#pragma unroll
        for (int r = 0; r < 4; ++r) {
          const int row = m0 + wm * 128 + mf * 16 + lg * 4 + r;
          Cf[row * N + col] = acc[mf][nf][r] + bv;
        }
    }
  }
}

// ---------------- in-place partial rotary on Q and K ----------------
__global__ __launch_bounds__(256) void rope_kernel(unsigned short* __restrict__ Q,
                                                   unsigned short* __restrict__ K,
                                                   const float* __restrict__ cosb,
                                                   const float* __restrict__ sinb) {
  const int idx = blockIdx.x * 256 + threadIdx.x;  // B*H*S*16
  const int i = idx & 15;
  const int s = (idx >> 4) & 1023;
  const int bh = idx >> 14;
  const int b = bh >> 5;
  const int t = b * SEQ + s;
  const float c = cosb[t * 16 + i];
  const float sn = sinb[t * 16 + i];
  const int base = (bh * SEQ + s) * DH;
  float q1 = bf2f(Q[base + i]), q2 = bf2f(Q[base + 16 + i]);
  Q[base + i] = f2bf(q1 * c - q2 * sn);
  Q[base + 16 + i] = f2bf(q2 * c + q1 * sn);
  float k1 = bf2f(K[base + i]), k2 = bf2f(K[base + 16 + i]);
  K[base + i] = f2bf(k1 * c - k2 * sn);
  K[base + 16 + i] = f2bf(k2 * c + k1 * sn);
}

// ---------------- flash attention ----------------
// grid: (S/128, B*H). 512 threads = 8 waves; wave w owns q-rows
// [qt*128 + w*16, +16). V arrives already transposed ([B][H][D][S]).
__global__ __launch_bounds__(512) void attn_kernel(const unsigned short* __restrict__ Qb,
                                                   const unsigned short* __restrict__ Kb,
                                                   const unsigned short* __restrict__ Vg,
                                                   unsigned short* __restrict__ Ob) {
  __shared__ __align__(16) unsigned short Klds[64][104];  // D padded 80->96, stride 104
  __shared__ __align__(16) unsigned short Vt[80][72];     // V^T tile [d][k]
  __shared__ __align__(16) unsigned short Plds[8][16][72];
  const int tid = threadIdx.x;
  const int lane = tid & 63, w = tid >> 6;
  const int lr = lane & 15, lg = lane >> 4;
  const int koff = lg * 8;
  const int qt = blockIdx.x, bh = blockIdx.y;
  const int h = bh & 31;
  const int base = bh * (SEQ * DH);   // Q,K: [B][H][S][D]
  const int vbase = bh * (DH * SEQ);  // V:   [B][H][D][S]

  for (int e = tid; e < 64 * 16; e += 512) Klds[e >> 4][80 + (e & 15)] = 0;

  const int rowbase = qt * 128 + w * 16;
  const int qrow = rowbase + lr;
  bf16x8 qf[3];
#pragma unroll
  for (int c = 0; c < 3; ++c) {
    const int d = c * 32 + koff;
    if (d < DH)
      qf[c] = *(const bf16x8*)(Qb + base + qrow * DH + d);
    else
      qf[c] = (bf16x8)(__bf16)0.0f;
  }

  float m[4], l[4];
  f32x4 of[5];
#pragma unroll
  for (int r = 0; r < 4; ++r) {
    m[r] = -3.0e38f;
    l[r] = 0.0f;
  }
#pragma unroll
  for (int d = 0; d < 5; ++d) of[d] = (f32x4)0.0f;

  const int ktmax = 2 * qt + 1;
  for (int kt = 0; kt <= ktmax; ++kt) {
    __syncthreads();
    for (int e = tid; e < 640; e += 512) {
      const int r = e / 10, dc = (e - r * 10) * 8;
      *(bf16x8*)&Klds[r][dc] = *(const bf16x8*)(Kb + base + (kt * 64 + r) * DH + dc);
    }
    for (int e = tid; e < 640; e += 512) {
      const int d = e >> 3, sc = (e & 7) * 8;
      *(bf16x8*)&Vt[d][sc] = *(const bf16x8*)(Vg + vbase + d * SEQ + kt * 64 + sc);
    }
    __syncthreads();

    if (kt * 64 > rowbase + 15) continue;

    f32x4 sc[4];
#pragma unroll
    for (int cf = 0; cf < 4; ++cf) sc[cf] = (f32x4)0.0f;
#pragma unroll
    for (int c = 0; c < 3; ++c) {
#pragma unroll
      for (int cf = 0; cf < 4; ++cf) {
        bf16x8 kb = *(const bf16x8*)&Klds[cf * 16 + lr][c * 32 + koff];
        sc[cf] = __builtin_amdgcn_mfma_f32_16x16x32_bf16(qf[c], kb, sc[cf], 0, 0, 0);
      }
    }

    const int rowg = rowbase + lg * 4;
#pragma unroll
    for (int cf = 0; cf < 4; ++cf) {
      const int colg = kt * 64 + cf * 16 + lr;
#pragma unroll
      for (int r = 0; r < 4; ++r) {
        float v = sc[cf][r] * SM_SCALE;
        if (colg > rowg + r) v = -1.0e30f;
        sc[cf][r] = v;
      }
    }

    float al[4];
#pragma unroll
    for (int r = 0; r < 4; ++r) {
      float mx = fmaxf(fmaxf(sc[0][r], sc[1][r]), fmaxf(sc[2][r], sc[3][r]));
#pragma unroll
      for (int off = 1; off < 16; off <<= 1) mx = fmaxf(mx, __shfl_xor(mx, off, 64));
      const float mnew = fmaxf(m[r], mx);
      al[r] = __expf(m[r] - mnew);
      m[r] = mnew;
    }
    float ls[4] = {0.f, 0.f, 0.f, 0.f};
#pragma unroll
    for (int cf = 0; cf < 4; ++cf)
#pragma unroll
      for (int r = 0; r < 4; ++r) {
        const float p = __expf(sc[cf][r] - m[r]);
        sc[cf][r] = p;
        ls[r] += p;
      }
#pragma unroll
    for (int r = 0; r < 4; ++r) {
      float sv = ls[r];
#pragma unroll
      for (int off = 1; off < 16; off <<= 1) sv += __shfl_xor(sv, off, 64);
      l[r] = l[r] * al[r] + sv;
    }
#pragma unroll
    for (int d = 0; d < 5; ++d)
#pragma unroll
      for (int r = 0; r < 4; ++r) of[d][r] *= al[r];

#pragma unroll
    for (int cf = 0; cf < 4; ++cf)
#pragma unroll
      for (int r = 0; r < 4; ++r)
        Plds[w][lg * 4 + r][cf * 16 + lr] = f2bf(sc[cf][r]);

#pragma unroll
    for (int kc = 0; kc < 2; ++kc) {
      bf16x8 pa = *(const bf16x8*)&Plds[w][lr][kc * 32 + koff];
#pragma unroll
      for (int d = 0; d < 5; ++d) {
        bf16x8 vb = *(const bf16x8*)&Vt[d * 16 + lr][kc * 32 + koff];
        of[d] = __builtin_amdgcn_mfma_f32_16x16x32_bf16(pa, vb, of[d], 0, 0, 0);
      }
    }
  }

  const int t = (bh >> 5) * SEQ + rowbase + lg * 4;
#pragma unroll
  for (int r = 0; r < 4; ++r) {
    const float rl = 1.0f / l[r];
#pragma unroll
    for (int d = 0; d < 5; ++d)
      Ob[(t + r) * HID + h * DH + d * 16 + lr] = f2bf(of[d][r] * rl);
  }
}

// ---------------- launch ----------------
extern "C" void kernel_launch(void* const* d_in, const int* in_sizes, int n_in,
                              void* d_out, int out_size, void* d_ws, size_t ws_size,
                              hipStream_t stream) {
  const float* hs = (const float*)d_in[0];
  const float* cosb = (const float*)d_in[1];
  const float* sinb = (const float*)d_in[2];
  const float* w_qkv = (const float*)d_in[3];
  const float* b_qkv = (const float*)d_in[4];
  const float* w_dense = (const float*)d_in[5];
  const float* b_dense = (const float*)d_in[6];
  float* out = (float*)d_out;
  char* ws = (char*)d_ws;

  // workspace layout (total ~123.2 MB)
  unsigned short* hsb = (unsigned short*)(ws + 0);         // 21.0 MB (T*HID bf16)
  unsigned short* aob = (unsigned short*)(ws + 0);         // alias (attn out)
  unsigned short* wqb = (unsigned short*)(ws + 20971520);  // 39.3 MB
  unsigned short* wdb = (unsigned short*)(ws + 20971520);  // alias (after gemm1)
  unsigned short* Qb = (unsigned short*)(ws + 60293120);   // 21.0 MB
  unsigned short* Kb = (unsigned short*)(ws + 81264640);   // 21.0 MB
  unsigned short* Vb = (unsigned short*)(ws + 102236160);  // 21.0 MB ([B][H][D][S])

  cvt_kernel<<<2048, 256, 0, stream>>>(hs, hsb, (NT * HID) / 4);
  cvt_kernel<<<2048, 256, 0, stream>>>(w_qkv, wqb, (NQKV * HID) / 4);
  gemm8p_kernel<0><<<dim3(NQKV / 256, NT / 256), 512, 0, stream>>>(
      hsb, wqb, b_qkv, Qb, Kb, Vb, nullptr, NT, NQKV, HID);
  cvt_kernel<<<2048, 256, 0, stream>>>(w_dense, wdb, (HID * HID) / 4);
  rope_kernel<<<(NB * NH * SEQ * 16) / 256, 256, 0, stream>>>(Qb, Kb, cosb, sinb);
  attn_kernel<<<dim3(SEQ / 128, NB * NH), 512, 0, stream>>>(Qb, Kb, Vb, aob);
  gemm8p_kernel<1><<<dim3(HID / 256, NT / 256), 512, 0, stream>>>(
      aob, wdb, b_dense, nullptr, nullptr, nullptr, out, NT, HID, HID);
}

// Round 10
// 412.421 us; speedup vs baseline: 4.4831x; 1.0710x over previous
//
#include <hip/hip_runtime.h>

typedef __attribute__((ext_vector_type(8))) __bf16 bf16x8;
typedef __attribute__((ext_vector_type(4))) float f32x4;

#define NH 32
#define DH 80
#define SEQ 1024
#define NB 4
#define NT 4096
#define HID 2560
#define NQKV 7680
#define SM_SCALE 0.11180339887498948f

static __device__ __forceinline__ unsigned short f2bf(float f) {
  unsigned u = __builtin_bit_cast(unsigned, f);
  u += 0x7fffu + ((u >> 16) & 1u);
  return (unsigned short)(u >> 16);
}
static __device__ __forceinline__ float bf2f(unsigned short s) {
  unsigned u = (unsigned)s << 16;
  return __builtin_bit_cast(float, u);
}

typedef __attribute__((address_space(1))) const unsigned int as1_uint;
typedef __attribute__((address_space(3))) unsigned int as3_uint;
static __device__ __forceinline__ void gload16(const void* g, void* l) {
  __builtin_amdgcn_global_load_lds((as1_uint*)g, (as3_uint*)l, 16, 0, 0);
}

// ---------------- fp32 -> bf16 convert (vectorized) ----------------
__global__ __launch_bounds__(256) void cvt_kernel(const float* __restrict__ in,
                                                  unsigned short* __restrict__ out,
                                                  int n4) {
  const float4* __restrict__ in4 = (const float4*)in;
  ushort4* __restrict__ out4 = (ushort4*)out;
  for (int i = blockIdx.x * blockDim.x + threadIdx.x; i < n4;
       i += gridDim.x * blockDim.x) {
    float4 v = in4[i];
    ushort4 o;
    o.x = f2bf(v.x);
    o.y = f2bf(v.y);
    o.z = f2bf(v.z);
    o.w = f2bf(v.w);
    out4[i] = o;
  }
}

// ------------- 256x256 8-phase pipelined bf16 GEMM: C = A @ B^T + bias -------
// (unchanged from round 9 — 189.6us QKV, MfmaUtil 36%)
template <int EPI>
__global__ __launch_bounds__(512, 2) void gemm8p_kernel(
    const unsigned short* __restrict__ A, const unsigned short* __restrict__ Bm,
    const float* __restrict__ bias, unsigned short* __restrict__ Cq,
    unsigned short* __restrict__ Ck, unsigned short* __restrict__ Cv,
    float* __restrict__ Cf, int M, int N, int K) {
  __shared__ __align__(16) unsigned short AL[2][2][8192];  // [buf][half][128*64]
  __shared__ __align__(16) unsigned short BL[2][2][8192];
  const int tid = threadIdx.x;
  const int lane = tid & 63, w = tid >> 6;
  const int wm = w >> 2, wn = w & 3;
  const int lr = lane & 15, lg = lane >> 4;
  const int bhh = wn >> 1;
  const int brow = (wn & 1) * 64;

  const int gx = gridDim.x;
  const int nwg = gx * gridDim.y;
  int bid = blockIdx.y * gx + blockIdx.x;
  bid = (bid & 7) * (nwg >> 3) + (bid >> 3);
  const int n0 = (bid % gx) * 256;
  const int m0 = (bid / gx) * 256;

  const unsigned short* asrc[2][2];
  const unsigned short* bsrc[2][2];
#pragma unroll
  for (int h = 0; h < 2; ++h)
#pragma unroll
    for (int j = 0; j < 2; ++j) {
      const int off = j * 8192 + tid * 16;
      const int u = off ^ (((off >> 7) & 7) << 4);
      const int row = u >> 7, col = (u & 127) >> 1;
      asrc[h][j] = A + (size_t)(m0 + h * 128 + row) * K + col;
      bsrc[h][j] = Bm + (size_t)(n0 + h * 128 + row) * K + col;
    }

  const int NK = K >> 6, NIT = NK >> 1;

#define SA(buf, h, kt)                                                     \
  do {                                                                     \
    gload16(asrc[h][0] + (size_t)(kt) * 64,                                \
            (char*)&AL[buf][h][0] + w * 1024);                             \
    gload16(asrc[h][1] + (size_t)(kt) * 64,                                \
            (char*)&AL[buf][h][0] + 8192 + w * 1024);                      \
  } while (0)
#define SB(buf, h, kt)                                                     \
  do {                                                                     \
    gload16(bsrc[h][0] + (size_t)(kt) * 64,                                \
            (char*)&BL[buf][h][0] + w * 1024);                             \
    gload16(bsrc[h][1] + (size_t)(kt) * 64,                                \
            (char*)&BL[buf][h][0] + 8192 + w * 1024);                      \
  } while (0)
#define FA(buf, lrow, ks)                                                  \
  (*(const bf16x8*)((const char*)&AL[buf][wm][0] +                         \
                    (((lrow) * 128 + (ks) * 64 + lg * 16) ^                \
                     (((lrow) & 7) << 4))))
#define FB(buf, lrow, ks)                                                  \
  (*(const bf16x8*)((const char*)&BL[buf][bhh][0] +                        \
                    (((lrow) * 128 + (ks) * 64 + lg * 16) ^                \
                     (((lrow) & 7) << 4))))
#define PH_MFMA(AIDX, NBASE, BREG)                                         \
  __builtin_amdgcn_s_barrier();                                            \
  __builtin_amdgcn_s_setprio(1);                                           \
  _Pragma("unroll") for (int mf = 0; mf < 4; ++mf)                         \
      _Pragma("unroll") for (int nf = 0; nf < 2; ++nf) {                   \
    acc[AIDX + mf][NBASE + nf] = __builtin_amdgcn_mfma_f32_16x16x32_bf16(  \
        af[mf * 2 + 0], BREG[nf * 2 + 0], acc[AIDX + mf][NBASE + nf], 0, 0, 0); \
    acc[AIDX + mf][NBASE + nf] = __builtin_amdgcn_mfma_f32_16x16x32_bf16(  \
        af[mf * 2 + 1], BREG[nf * 2 + 1], acc[AIDX + mf][NBASE + nf], 0, 0, 0); \
  }                                                                        \
  __builtin_amdgcn_s_setprio(0);

  f32x4 acc[8][4];
#pragma unroll
  for (int i = 0; i < 8; ++i)
#pragma unroll
    for (int j = 0; j < 4; ++j) acc[i][j] = (f32x4)0.0f;

  SB(0, 0, 0); SA(0, 0, 0); SB(0, 1, 0); SA(0, 1, 0);
  SB(1, 0, 1); SA(1, 0, 1);
  asm volatile("s_waitcnt vmcnt(4)" ::: "memory");
  __builtin_amdgcn_s_barrier();

  bf16x8 af[8], bl[4], bhf[4];

  for (int i = 0; i < NIT; ++i) {
    const int t1 = 2 * i + 1, t2 = 2 * i + 2, t3 = 2 * i + 3;
    const bool p2 = t2 < NK, p3 = t3 < NK;

#pragma unroll
    for (int mf = 0; mf < 4; ++mf) {
      af[mf * 2 + 0] = FA(0, mf * 16 + lr, 0);
      af[mf * 2 + 1] = FA(0, mf * 16 + lr, 1);
    }
#pragma unroll
    for (int nf = 0; nf < 2; ++nf) {
      bl[nf * 2 + 0] = FB(0, brow + nf * 16 + lr, 0);
      bl[nf * 2 + 1] = FB(0, brow + nf * 16 + lr, 1);
    }
    SB(1, 1, t1);
    PH_MFMA(0, 0, bl)
    __builtin_amdgcn_s_barrier();
#pragma unroll
    for (int nf = 0; nf < 2; ++nf) {
      bhf[nf * 2 + 0] = FB(0, brow + (nf + 2) * 16 + lr, 0);
      bhf[nf * 2 + 1] = FB(0, brow + (nf + 2) * 16 + lr, 1);
    }
    SA(1, 1, t1);
    PH_MFMA(0, 2, bhf)
    __builtin_amdgcn_s_barrier();
#pragma unroll
    for (int mf = 0; mf < 4; ++mf) {
      af[mf * 2 + 0] = FA(0, 64 + mf * 16 + lr, 0);
      af[mf * 2 + 1] = FA(0, 64 + mf * 16 + lr, 1);
    }
    if (p2) SB(0, 0, t2);
    PH_MFMA(4, 0, bl)
    __builtin_amdgcn_s_barrier();
    if (p2) SA(0, 0, t2);
    PH_MFMA(4, 2, bhf)
    if (i + 1 < NIT)
      asm volatile("s_waitcnt vmcnt(4)" ::: "memory");
    else
      asm volatile("s_waitcnt vmcnt(0)" ::: "memory");
    __builtin_amdgcn_s_barrier();

#pragma unroll
    for (int mf = 0; mf < 4; ++mf) {
      af[mf * 2 + 0] = FA(1, mf * 16 + lr, 0);
      af[mf * 2 + 1] = FA(1, mf * 16 + lr, 1);
    }
#pragma unroll
    for (int nf = 0; nf < 2; ++nf) {
      bl[nf * 2 + 0] = FB(1, brow + nf * 16 + lr, 0);
      bl[nf * 2 + 1] = FB(1, brow + nf * 16 + lr, 1);
    }
    if (p2) SB(0, 1, t2);
    PH_MFMA(0, 0, bl)
    __builtin_amdgcn_s_barrier();
#pragma unroll
    for (int nf = 0; nf < 2; ++nf) {
      bhf[nf * 2 + 0] = FB(1, brow + (nf + 2) * 16 + lr, 0);
      bhf[nf * 2 + 1] = FB(1, brow + (nf + 2) * 16 + lr, 1);
    }
    if (p2) SA(0, 1, t2);
    PH_MFMA(0, 2, bhf)
    __builtin_amdgcn_s_barrier();
#pragma unroll
    for (int mf = 0; mf < 4; ++mf) {
      af[mf * 2 + 0] = FA(1, 64 + mf * 16 + lr, 0);
      af[mf * 2 + 1] = FA(1, 64 + mf * 16 + lr, 1);
    }
    if (p3) SB(1, 0, t3);
    PH_MFMA(4, 0, bl)
    __builtin_amdgcn_s_barrier();
    if (p3) SA(1, 0, t3);
    PH_MFMA(4, 2, bhf)
    if (i + 1 < NIT) asm volatile("s_waitcnt vmcnt(4)" ::: "memory");
    __builtin_amdgcn_s_barrier();
  }
#undef SA
#undef SB
#undef FA
#undef FB
#undef PH_MFMA

  if (EPI == 0) {
    if (n0 >= 2 * HID) {
      unsigned short* scr = (unsigned short*)&AL[0][0][0] + w * 2176;
      const int bb = (m0 + wm * 128) >> 10;
      const int ssb = (m0 + wm * 128) & 1023;
#pragma unroll
      for (int nf = 0; nf < 4; ++nf) {
        const int col0 = n0 - 2 * HID + wn * 64 + nf * 16;
        const int hh = col0 / DH;
        const int dd0 = col0 - hh * DH;
        const float bv = bias[2 * HID + col0 + lr];
#pragma unroll
        for (int mf = 0; mf < 8; ++mf) {
          ushort4 p;
          p.x = f2bf(acc[mf][nf][0] + bv);
          p.y = f2bf(acc[mf][nf][1] + bv);
          p.z = f2bf(acc[mf][nf][2] + bv);
          p.w = f2bf(acc[mf][nf][3] + bv);
          *(ushort4*)&scr[lr * 136 + mf * 16 + lg * 4] = p;
        }
#pragma unroll
        for (int it = 0; it < 4; ++it) {
          const int dd = (lane >> 4) + it * 4;
          const int sl = (lane & 15) * 8;
          bf16x8 v = *(const bf16x8*)&scr[dd * 136 + sl];
          *(bf16x8*)(Cv + ((size_t)(bb * NH + hh) * DH + dd0 + dd) * SEQ + ssb + sl) = v;
        }
        asm volatile("s_waitcnt lgkmcnt(0)" ::: "memory");
      }
    } else {
#pragma unroll
      for (int nf = 0; nf < 4; ++nf) {
        const int col = n0 + wn * 64 + nf * 16 + lr;
        const int sec = col >= HID ? 1 : 0;
        const int rem = col - sec * HID;
        const int hh = rem / DH;
        const int dd = rem - hh * DH;
        unsigned short* dst = sec ? Ck : Cq;
        const float bv = bias[col];
#pragma unroll
        for (int mf = 0; mf < 8; ++mf) {
#pragma unroll
          for (int r = 0; r < 4; ++r) {
            const int tr = m0 + wm * 128 + mf * 16 + lg * 4 + r;
            const int bb2 = tr >> 10, ss = tr & 1023;
            dst[((size_t)(bb2 * NH + hh) * SEQ + ss) * DH + dd] =
                f2bf(acc[mf][nf][r] + bv);
          }
        }
      }
    }
  } else {
#pragma unroll
    for (int nf = 0; nf < 4; ++nf) {
      const int col = n0 + wn * 64 + nf * 16 + lr;
      const float bv = bias[col];
#pragma unroll
      for (int mf = 0; mf < 8; ++mf)
#pragma unroll
        for (int r = 0; r < 4; ++r) {
          const int row = m0 + wm * 128 + mf * 16 + lg * 4 + r;
          Cf[row * N + col] = acc[mf][nf][r] + bv;
        }
    }
  }
}

// ---------------- in-place partial rotary on Q and K ----------------
__global__ __launch_bounds__(256) void rope_kernel(unsigned short* __restrict__ Q,
                                                   unsigned short* __restrict__ K,
                                                   const float* __restrict__ cosb,
                                                   const float* __restrict__ sinb) {
  const int idx = blockIdx.x * 256 + threadIdx.x;  // B*H*S*16
  const int i = idx & 15;
  const int s = (idx >> 4) & 1023;
  const int bh = idx >> 14;
  const int b = bh >> 5;
  const int t = b * SEQ + s;
  const float c = cosb[t * 16 + i];
  const float sn = sinb[t * 16 + i];
  const int base = (bh * SEQ + s) * DH;
  float q1 = bf2f(Q[base + i]), q2 = bf2f(Q[base + 16 + i]);
  Q[base + i] = f2bf(q1 * c - q2 * sn);
  Q[base + 16 + i] = f2bf(q2 * c + q1 * sn);
  float k1 = bf2f(K[base + i]), k2 = bf2f(K[base + 16 + i]);
  K[base + i] = f2bf(k1 * c - k2 * sn);
  K[base + 16 + i] = f2bf(k2 * c + k1 * sn);
}

// ---------------- flash attention (v2: QBLK=256, 8 waves x 32 q-rows) -------
// grid: (S/256, B*H). 512 threads = 8 waves; wave w owns q-rows
// [qt*256 + w*32, +32). V arrives transposed ([B][H][D][S]).
// T14 async-stage: tile kt+1's global loads issue right after the post-write
// barrier and sit in registers while tile kt computes; ds_writes at next top.
__global__ __launch_bounds__(512) void attn_kernel(const unsigned short* __restrict__ Qb,
                                                   const unsigned short* __restrict__ Kb,
                                                   const unsigned short* __restrict__ Vg,
                                                   unsigned short* __restrict__ Ob) {
  __shared__ __align__(16) unsigned short Klds[64][104];  // D padded 80->96
  __shared__ __align__(16) unsigned short Vt[80][72];     // V^T tile [d][k]
  __shared__ __align__(16) unsigned short Plds[8][32][72];
  const int tid = threadIdx.x;
  const int lane = tid & 63, w = tid >> 6;
  const int lr = lane & 15, lg = lane >> 4;
  const int koff = lg * 8;
  const int qt = blockIdx.x, bh = blockIdx.y;
  const int h = bh & 31;
  const int base = bh * (SEQ * DH);   // Q,K: [B][H][S][D]
  const int vbase = bh * (DH * SEQ);  // V:   [B][H][D][S]

  for (int e = tid; e < 64 * 16; e += 512) Klds[e >> 4][80 + (e & 15)] = 0;

  const int rowbase = qt * 256 + w * 32;
  bf16x8 qf[2][3];
#pragma unroll
  for (int hh = 0; hh < 2; ++hh)
#pragma unroll
    for (int c = 0; c < 3; ++c) {
      const int d = c * 32 + koff;
      if (d < DH)
        qf[hh][c] =
            *(const bf16x8*)(Qb + base + (rowbase + hh * 16 + lr) * DH + d);
      else
        qf[hh][c] = (bf16x8)(__bf16)0.0f;
    }

  float m[2][4], l[2][4];
  f32x4 of[2][5];
#pragma unroll
  for (int hh = 0; hh < 2; ++hh) {
#pragma unroll
    for (int r = 0; r < 4; ++r) {
      m[hh][r] = -3.0e38f;
      l[hh][r] = 0.0f;
    }
#pragma unroll
    for (int d = 0; d < 5; ++d) of[hh][d] = (f32x4)0.0f;
  }

  // staging coords (fixed per thread)
  const int ke0r = tid / 10, ke0c = (tid - (tid / 10) * 10) * 8;
  const int ke1 = tid + 512;
  const int ke1r = ke1 / 10, ke1c = (ke1 - (ke1 / 10) * 10) * 8;
  const int ve0d = tid >> 3, ve0c = (tid & 7) * 8;
  const int ve1d = (tid + 512) >> 3, ve1c = ((tid + 512) & 7) * 8;

  bf16x8 kreg0, kreg1, vreg0, vreg1;
  // prologue: load tile 0 into regs
  kreg0 = *(const bf16x8*)(Kb + base + ke0r * DH + ke0c);
  if (tid < 128) kreg1 = *(const bf16x8*)(Kb + base + ke1r * DH + ke1c);
  vreg0 = *(const bf16x8*)(Vg + vbase + ve0d * SEQ + ve0c);
  if (tid < 128) vreg1 = *(const bf16x8*)(Vg + vbase + ve1d * SEQ + ve1c);

  const int ktmax = 4 * qt + 3;
  for (int kt = 0; kt <= ktmax; ++kt) {
    __syncthreads();  // previous tile's LDS reads complete
    *(bf16x8*)&Klds[ke0r][ke0c] = kreg0;
    if (tid < 128) *(bf16x8*)&Klds[ke1r][ke1c] = kreg1;
    *(bf16x8*)&Vt[ve0d][ve0c] = vreg0;
    if (tid < 128) *(bf16x8*)&Vt[ve1d][ve1c] = vreg1;
    __syncthreads();  // tile visible

    // T14: issue next tile's loads now; they land during compute
    if (kt < ktmax) {
      const int nb = (kt + 1) * 64;
      kreg0 = *(const bf16x8*)(Kb + base + (nb + ke0r) * DH + ke0c);
      if (tid < 128) kreg1 = *(const bf16x8*)(Kb + base + (nb + ke1r) * DH + ke1c);
      vreg0 = *(const bf16x8*)(Vg + vbase + ve0d * SEQ + nb + ve0c);
      if (tid < 128) vreg1 = *(const bf16x8*)(Vg + vbase + ve1d * SEQ + nb + ve1c);
    }

    if (kt * 64 > rowbase + 31) continue;  // fully masked for this wave

    // S = Q K^T  (wave computes 32x64; K-frag read once, used for both halves)
    f32x4 sc[2][4];
#pragma unroll
    for (int hh = 0; hh < 2; ++hh)
#pragma unroll
      for (int cf = 0; cf < 4; ++cf) sc[hh][cf] = (f32x4)0.0f;
#pragma unroll
    for (int c = 0; c < 3; ++c) {
#pragma unroll
      for (int cf = 0; cf < 4; ++cf) {
        bf16x8 kb = *(const bf16x8*)&Klds[cf * 16 + lr][c * 32 + koff];
        sc[0][cf] = __builtin_amdgcn_mfma_f32_16x16x32_bf16(qf[0][c], kb, sc[0][cf], 0, 0, 0);
        sc[1][cf] = __builtin_amdgcn_mfma_f32_16x16x32_bf16(qf[1][c], kb, sc[1][cf], 0, 0, 0);
      }
    }

#pragma unroll
    for (int hh = 0; hh < 2; ++hh) {
      const int rowg = rowbase + hh * 16 + lg * 4;
#pragma unroll
      for (int cf = 0; cf < 4; ++cf) {
        const int colg = kt * 64 + cf * 16 + lr;
#pragma unroll
        for (int r = 0; r < 4; ++r) {
          float v = sc[hh][cf][r] * SM_SCALE;
          if (colg > rowg + r) v = -1.0e30f;
          sc[hh][cf][r] = v;
        }
      }
      float al[4];
#pragma unroll
      for (int r = 0; r < 4; ++r) {
        float mx = fmaxf(fmaxf(sc[hh][0][r], sc[hh][1][r]),
                         fmaxf(sc[hh][2][r], sc[hh][3][r]));
#pragma unroll
        for (int off = 1; off < 16; off <<= 1) mx = fmaxf(mx, __shfl_xor(mx, off, 64));
        const float mnew = fmaxf(m[hh][r], mx);
        al[r] = __expf(m[hh][r] - mnew);
        m[hh][r] = mnew;
      }
      float ls[4] = {0.f, 0.f, 0.f, 0.f};
#pragma unroll
      for (int cf = 0; cf < 4; ++cf)
#pragma unroll
        for (int r = 0; r < 4; ++r) {
          const float p = __expf(sc[hh][cf][r] - m[hh][r]);
          sc[hh][cf][r] = p;
          ls[r] += p;
        }
#pragma unroll
      for (int r = 0; r < 4; ++r) {
        float sv = ls[r];
#pragma unroll
        for (int off = 1; off < 16; off <<= 1) sv += __shfl_xor(sv, off, 64);
        l[hh][r] = l[hh][r] * al[r] + sv;
      }
#pragma unroll
      for (int d = 0; d < 5; ++d)
#pragma unroll
        for (int r = 0; r < 4; ++r) of[hh][d][r] *= al[r];
#pragma unroll
      for (int cf = 0; cf < 4; ++cf)
#pragma unroll
        for (int r = 0; r < 4; ++r)
          Plds[w][hh * 16 + lg * 4 + r][cf * 16 + lr] = f2bf(sc[hh][cf][r]);
    }

    // PV: V-frag read once, used for both halves
#pragma unroll
    for (int kc = 0; kc < 2; ++kc) {
      bf16x8 pa0 = *(const bf16x8*)&Plds[w][lr][kc * 32 + koff];
      bf16x8 pa1 = *(const bf16x8*)&Plds[w][16 + lr][kc * 32 + koff];
#pragma unroll
      for (int d = 0; d < 5; ++d) {
        bf16x8 vb = *(const bf16x8*)&Vt[d * 16 + lr][kc * 32 + koff];
        of[0][d] = __builtin_amdgcn_mfma_f32_16x16x32_bf16(pa0, vb, of[0][d], 0, 0, 0);
        of[1][d] = __builtin_amdgcn_mfma_f32_16x16x32_bf16(pa1, vb, of[1][d], 0, 0, 0);
      }
    }
  }

  // epilogue: normalize and write [T][HID] bf16
#pragma unroll
  for (int hh = 0; hh < 2; ++hh) {
    const int t = (bh >> 5) * SEQ + rowbase + hh * 16 + lg * 4;
#pragma unroll
    for (int r = 0; r < 4; ++r) {
      const float rl = 1.0f / l[hh][r];
#pragma unroll
      for (int d = 0; d < 5; ++d)
        Ob[(t + r) * HID + h * DH + d * 16 + lr] = f2bf(of[hh][d][r] * rl);
    }
  }
}

// ---------------- launch ----------------
extern "C" void kernel_launch(void* const* d_in, const int* in_sizes, int n_in,
                              void* d_out, int out_size, void* d_ws, size_t ws_size,
                              hipStream_t stream) {
  const float* hs = (const float*)d_in[0];
  const float* cosb = (const float*)d_in[1];
  const float* sinb = (const float*)d_in[2];
  const float* w_qkv = (const float*)d_in[3];
  const float* b_qkv = (const float*)d_in[4];
  const float* w_dense = (const float*)d_in[5];
  const float* b_dense = (const float*)d_in[6];
  float* out = (float*)d_out;
  char* ws = (char*)d_ws;

  // workspace layout (total ~123.2 MB)
  unsigned short* hsb = (unsigned short*)(ws + 0);         // 21.0 MB (T*HID bf16)
  unsigned short* aob = (unsigned short*)(ws + 0);         // alias (attn out)
  unsigned short* wqb = (unsigned short*)(ws + 20971520);  // 39.3 MB
  unsigned short* wdb = (unsigned short*)(ws + 20971520);  // alias (after gemm1)
  unsigned short* Qb = (unsigned short*)(ws + 60293120);   // 21.0 MB
  unsigned short* Kb = (unsigned short*)(ws + 81264640);   // 21.0 MB
  unsigned short* Vb = (unsigned short*)(ws + 102236160);  // 21.0 MB ([B][H][D][S])

  cvt_kernel<<<2048, 256, 0, stream>>>(hs, hsb, (NT * HID) / 4);
  cvt_kernel<<<2048, 256, 0, stream>>>(w_qkv, wqb, (NQKV * HID) / 4);
  gemm8p_kernel<0><<<dim3(NQKV / 256, NT / 256), 512, 0, stream>>>(
      hsb, wqb, b_qkv, Qb, Kb, Vb, nullptr, NT, NQKV, HID);
  cvt_kernel<<<2048, 256, 0, stream>>>(w_dense, wdb, (HID * HID) / 4);
  rope_kernel<<<(NB * NH * SEQ * 16) / 256, 256, 0, stream>>>(Qb, Kb, cosb, sinb);
  attn_kernel<<<dim3(SEQ / 256, NB * NH), 512, 0, stream>>>(Qb, Kb, Vb, aob);
  gemm8p_kernel<1><<<dim3(HID / 256, NT / 256), 512, 0, stream>>>(
      aob, wdb, b_dense, nullptr, nullptr, nullptr, out, NT, HID, HID);
}

// Round 11
// 398.576 us; speedup vs baseline: 4.6389x; 1.0347x over previous
//
#include <hip/hip_runtime.h>

typedef __attribute__((ext_vector_type(8))) __bf16 bf16x8;
typedef __attribute__((ext_vector_type(4))) float f32x4;

#define NH 32
#define DH 80
#define SEQ 1024
#define NB 4
#define NT 4096
#define HID 2560
#define NQKV 7680
#define SM_SCALE 0.11180339887498948f

static __device__ __forceinline__ unsigned short f2bf(float f) {
  unsigned u = __builtin_bit_cast(unsigned, f);
  u += 0x7fffu + ((u >> 16) & 1u);
  return (unsigned short)(u >> 16);
}
static __device__ __forceinline__ float bf2f(unsigned short s) {
  unsigned u = (unsigned)s << 16;
  return __builtin_bit_cast(float, u);
}

typedef __attribute__((address_space(1))) const unsigned int as1_uint;
typedef __attribute__((address_space(3))) unsigned int as3_uint;
static __device__ __forceinline__ void gload16(const void* g, void* l) {
  __builtin_amdgcn_global_load_lds((as1_uint*)g, (as3_uint*)l, 16, 0, 0);
}

// ---------------- fp32 -> bf16 convert (vectorized) ----------------
__global__ __launch_bounds__(256) void cvt_kernel(const float* __restrict__ in,
                                                  unsigned short* __restrict__ out,
                                                  int n4) {
  const float4* __restrict__ in4 = (const float4*)in;
  ushort4* __restrict__ out4 = (ushort4*)out;
  for (int i = blockIdx.x * blockDim.x + threadIdx.x; i < n4;
       i += gridDim.x * blockDim.x) {
    float4 v = in4[i];
    ushort4 o;
    o.x = f2bf(v.x);
    o.y = f2bf(v.y);
    o.z = f2bf(v.z);
    o.w = f2bf(v.w);
    out4[i] = o;
  }
}

// ------------- 256x256 8-phase pipelined bf16 GEMM: C = A @ B^T + bias -------
// Deep-pipeline variant: prologue stages t0+t1 (16 loads); in-loop staging at
// ph3 (B both halves, t+2), ph4 (A both, t+2), ph7 (B, t+3), ph8 (A, t+3) —
// legal because all B(buf) reads are consumed by each wave's own MFMA before
// ph2's post-MFMA barrier, and all A(buf) reads before ph3's. Uniform
// vmcnt(8) at ph4/ph8: waits only on loads issued 4-8 phases earlier; never
// drains in steady state (NK even => both prefetch flags coincide).
// LDS [buf][half][128][64] x(A,B) = 128 KiB, (row&7)<<4 XOR swizzle via
// pre-swizzled global source (linear DMA dest).
// EPI 0: q/k scatter [B][H][S][D]; V via in-LDS transpose -> [B][H][D][S].
// EPI 1: fp32 C.
template <int EPI>
__global__ __launch_bounds__(512, 2) void gemm8p_kernel(
    const unsigned short* __restrict__ A, const unsigned short* __restrict__ Bm,
    const float* __restrict__ bias, unsigned short* __restrict__ Cq,
    unsigned short* __restrict__ Ck, unsigned short* __restrict__ Cv,
    float* __restrict__ Cf, int M, int N, int K) {
  __shared__ __align__(16) unsigned short AL[2][2][8192];  // [buf][half][128*64]
  __shared__ __align__(16) unsigned short BL[2][2][8192];
  const int tid = threadIdx.x;
  const int lane = tid & 63, w = tid >> 6;
  const int wm = w >> 2, wn = w & 3;
  const int lr = lane & 15, lg = lane >> 4;
  const int bhh = wn >> 1;
  const int brow = (wn & 1) * 64;

  const int gx = gridDim.x;
  const int nwg = gx * gridDim.y;
  int bid = blockIdx.y * gx + blockIdx.x;
  bid = (bid & 7) * (nwg >> 3) + (bid >> 3);
  const int n0 = (bid % gx) * 256;
  const int m0 = (bid / gx) * 256;

  const unsigned short* asrc[2][2];
  const unsigned short* bsrc[2][2];
#pragma unroll
  for (int h = 0; h < 2; ++h)
#pragma unroll
    for (int j = 0; j < 2; ++j) {
      const int off = j * 8192 + tid * 16;
      const int u = off ^ (((off >> 7) & 7) << 4);
      const int row = u >> 7, col = (u & 127) >> 1;
      asrc[h][j] = A + (size_t)(m0 + h * 128 + row) * K + col;
      bsrc[h][j] = Bm + (size_t)(n0 + h * 128 + row) * K + col;
    }

  const int NK = K >> 6, NIT = NK >> 1;

#define SA(buf, h, kt)                                                     \
  do {                                                                     \
    gload16(asrc[h][0] + (size_t)(kt) * 64,                                \
            (char*)&AL[buf][h][0] + w * 1024);                             \
    gload16(asrc[h][1] + (size_t)(kt) * 64,                                \
            (char*)&AL[buf][h][0] + 8192 + w * 1024);                      \
  } while (0)
#define SB(buf, h, kt)                                                     \
  do {                                                                     \
    gload16(bsrc[h][0] + (size_t)(kt) * 64,                                \
            (char*)&BL[buf][h][0] + w * 1024);                             \
    gload16(bsrc[h][1] + (size_t)(kt) * 64,                                \
            (char*)&BL[buf][h][0] + 8192 + w * 1024);                      \
  } while (0)
#define FA(buf, lrow, ks)                                                  \
  (*(const bf16x8*)((const char*)&AL[buf][wm][0] +                         \
                    (((lrow) * 128 + (ks) * 64 + lg * 16) ^                \
                     (((lrow) & 7) << 4))))
#define FB(buf, lrow, ks)                                                  \
  (*(const bf16x8*)((const char*)&BL[buf][bhh][0] +                        \
                    (((lrow) * 128 + (ks) * 64 + lg * 16) ^                \
                     (((lrow) & 7) << 4))))
#define PH_MFMA(AIDX, NBASE, BREG)                                         \
  __builtin_amdgcn_s_barrier();                                            \
  __builtin_amdgcn_s_setprio(1);                                           \
  _Pragma("unroll") for (int mf = 0; mf < 4; ++mf)                         \
      _Pragma("unroll") for (int nf = 0; nf < 2; ++nf) {                   \
    acc[AIDX + mf][NBASE + nf] = __builtin_amdgcn_mfma_f32_16x16x32_bf16(  \
        af[mf * 2 + 0], BREG[nf * 2 + 0], acc[AIDX + mf][NBASE + nf], 0, 0, 0); \
    acc[AIDX + mf][NBASE + nf] = __builtin_amdgcn_mfma_f32_16x16x32_bf16(  \
        af[mf * 2 + 1], BREG[nf * 2 + 1], acc[AIDX + mf][NBASE + nf], 0, 0, 0); \
  }                                                                        \
  __builtin_amdgcn_s_setprio(0);

  f32x4 acc[8][4];
#pragma unroll
  for (int i = 0; i < 8; ++i)
#pragma unroll
    for (int j = 0; j < 4; ++j) acc[i][j] = (f32x4)0.0f;

  // prologue: stage tile0 (8 loads) + tile1 (8 loads); wait t0; barrier
  SB(0, 0, 0); SB(0, 1, 0); SA(0, 0, 0); SA(0, 1, 0);
  SB(1, 0, 1); SB(1, 1, 1); SA(1, 0, 1); SA(1, 1, 1);
  asm volatile("s_waitcnt vmcnt(8)" ::: "memory");
  __builtin_amdgcn_s_barrier();

  bf16x8 af[8], bl[4], bhf[4];

  for (int i = 0; i < NIT; ++i) {
    const int t2 = 2 * i + 2, t3 = 2 * i + 3;
    const bool pf = (i + 1) < NIT;  // NK even: t2<NK and t3<NK coincide

    // ---------- tile 2i (buf 0) ----------
    // ph1: quad(m-lo,n-lo)
#pragma unroll
    for (int mf = 0; mf < 4; ++mf) {
      af[mf * 2 + 0] = FA(0, mf * 16 + lr, 0);
      af[mf * 2 + 1] = FA(0, mf * 16 + lr, 1);
    }
#pragma unroll
    for (int nf = 0; nf < 2; ++nf) {
      bl[nf * 2 + 0] = FB(0, brow + nf * 16 + lr, 0);
      bl[nf * 2 + 1] = FB(0, brow + nf * 16 + lr, 1);
    }
    PH_MFMA(0, 0, bl)
    __builtin_amdgcn_s_barrier();
    // ph2: quad(m-lo,n-hi) — after this barrier ALL B(buf0) reads consumed
#pragma unroll
    for (int nf = 0; nf < 2; ++nf) {
      bhf[nf * 2 + 0] = FB(0, brow + (nf + 2) * 16 + lr, 0);
      bhf[nf * 2 + 1] = FB(0, brow + (nf + 2) * 16 + lr, 1);
    }
    PH_MFMA(0, 2, bhf)
    __builtin_amdgcn_s_barrier();
    // ph3: quad(m-hi,n-lo); stage B(t2) both halves into buf0
#pragma unroll
    for (int mf = 0; mf < 4; ++mf) {
      af[mf * 2 + 0] = FA(0, 64 + mf * 16 + lr, 0);
      af[mf * 2 + 1] = FA(0, 64 + mf * 16 + lr, 1);
    }
    if (pf) { SB(0, 0, t2); SB(0, 1, t2); }
    PH_MFMA(4, 0, bl)
    __builtin_amdgcn_s_barrier();
    // ph4: quad(m-hi,n-hi); stage A(t2); counted wait (t1 landed)
    if (pf) { SA(0, 0, t2); SA(0, 1, t2); }
    PH_MFMA(4, 2, bhf)
    if (pf)
      asm volatile("s_waitcnt vmcnt(8)" ::: "memory");
    else
      asm volatile("s_waitcnt vmcnt(0)" ::: "memory");
    __builtin_amdgcn_s_barrier();

    // ---------- tile 2i+1 (buf 1) ----------
    // ph5
#pragma unroll
    for (int mf = 0; mf < 4; ++mf) {
      af[mf * 2 + 0] = FA(1, mf * 16 + lr, 0);
      af[mf * 2 + 1] = FA(1, mf * 16 + lr, 1);
    }
#pragma unroll
    for (int nf = 0; nf < 2; ++nf) {
      bl[nf * 2 + 0] = FB(1, brow + nf * 16 + lr, 0);
      bl[nf * 2 + 1] = FB(1, brow + nf * 16 + lr, 1);
    }
    PH_MFMA(0, 0, bl)
    __builtin_amdgcn_s_barrier();
    // ph6
#pragma unroll
    for (int nf = 0; nf < 2; ++nf) {
      bhf[nf * 2 + 0] = FB(1, brow + (nf + 2) * 16 + lr, 0);
      bhf[nf * 2 + 1] = FB(1, brow + (nf + 2) * 16 + lr, 1);
    }
    PH_MFMA(0, 2, bhf)
    __builtin_amdgcn_s_barrier();
    // ph7: stage B(t3) both halves into buf1
#pragma unroll
    for (int mf = 0; mf < 4; ++mf) {
      af[mf * 2 + 0] = FA(1, 64 + mf * 16 + lr, 0);
      af[mf * 2 + 1] = FA(1, 64 + mf * 16 + lr, 1);
    }
    if (pf) { SB(1, 0, t3); SB(1, 1, t3); }
    PH_MFMA(4, 0, bl)
    __builtin_amdgcn_s_barrier();
    // ph8: stage A(t3); counted wait (t2 landed)
    if (pf) { SA(1, 0, t3); SA(1, 1, t3); }
    PH_MFMA(4, 2, bhf)
    if (pf) asm volatile("s_waitcnt vmcnt(8)" ::: "memory");
    __builtin_amdgcn_s_barrier();
  }
#undef SA
#undef SB
#undef FA
#undef FB
#undef PH_MFMA

  if (EPI == 0) {
    if (n0 >= 2 * HID) {
      unsigned short* scr = (unsigned short*)&AL[0][0][0] + w * 2176;
      const int bb = (m0 + wm * 128) >> 10;
      const int ssb = (m0 + wm * 128) & 1023;
#pragma unroll
      for (int nf = 0; nf < 4; ++nf) {
        const int col0 = n0 - 2 * HID + wn * 64 + nf * 16;
        const int hh = col0 / DH;
        const int dd0 = col0 - hh * DH;
        const float bv = bias[2 * HID + col0 + lr];
#pragma unroll
        for (int mf = 0; mf < 8; ++mf) {
          ushort4 p;
          p.x = f2bf(acc[mf][nf][0] + bv);
          p.y = f2bf(acc[mf][nf][1] + bv);
          p.z = f2bf(acc[mf][nf][2] + bv);
          p.w = f2bf(acc[mf][nf][3] + bv);
          *(ushort4*)&scr[lr * 136 + mf * 16 + lg * 4] = p;
        }
#pragma unroll
        for (int it = 0; it < 4; ++it) {
          const int dd = (lane >> 4) + it * 4;
          const int sl = (lane & 15) * 8;
          bf16x8 v = *(const bf16x8*)&scr[dd * 136 + sl];
          *(bf16x8*)(Cv + ((size_t)(bb * NH + hh) * DH + dd0 + dd) * SEQ + ssb + sl) = v;
        }
        asm volatile("s_waitcnt lgkmcnt(0)" ::: "memory");
      }
    } else {
#pragma unroll
      for (int nf = 0; nf < 4; ++nf) {
        const int col = n0 + wn * 64 + nf * 16 + lr;
        const int sec = col >= HID ? 1 : 0;
        const int rem = col - sec * HID;
        const int hh = rem / DH;
        const int dd = rem - hh * DH;
        unsigned short* dst = sec ? Ck : Cq;
        const float bv = bias[col];
#pragma unroll
        for (int mf = 0; mf < 8; ++mf) {
#pragma unroll
          for (int r = 0; r < 4; ++r) {
            const int tr = m0 + wm * 128 + mf * 16 + lg * 4 + r;
            const int bb2 = tr >> 10, ss = tr & 1023;
            dst[((size_t)(bb2 * NH + hh) * SEQ + ss) * DH + dd] =
                f2bf(acc[mf][nf][r] + bv);
          }
        }
      }
    }
  } else {
#pragma unroll
    for (int nf = 0; nf < 4; ++nf) {
      const int col = n0 + wn * 64 + nf * 16 + lr;
      const float bv = bias[col];
#pragma unroll
      for (int mf = 0; mf < 8; ++mf)
#pragma unroll
        for (int r = 0; r < 4; ++r) {
          const int row = m0 + wm * 128 + mf * 16 + lg * 4 + r;
          Cf[row * N + col] = acc[mf][nf][r] + bv;
        }
    }
  }
}

// ------- in-place partial rotary on Q,K; Q additionally pre-scaled -------
__global__ __launch_bounds__(256) void rope_kernel(unsigned short* __restrict__ Q,
                                                   unsigned short* __restrict__ K,
                                                   const float* __restrict__ cosb,
                                                   const float* __restrict__ sinb) {
  const int idx = blockIdx.x * 256 + threadIdx.x;  // B*H*S*16
  const int i = idx & 15;
  const int s = (idx >> 4) & 1023;
  const int bh = idx >> 14;
  const int b = bh >> 5;
  const int t = b * SEQ + s;
  const float c = cosb[t * 16 + i];
  const float sn = sinb[t * 16 + i];
  const int base = (bh * SEQ + s) * DH;
  float q1 = bf2f(Q[base + i]), q2 = bf2f(Q[base + 16 + i]);
  Q[base + i] = f2bf((q1 * c - q2 * sn) * SM_SCALE);
  Q[base + 16 + i] = f2bf((q2 * c + q1 * sn) * SM_SCALE);
  // pre-scale the pass-through Q dims (32..79)
#pragma unroll
  for (int j = 0; j < 3; ++j) {
    const int d = 32 + j * 16 + i;
    Q[base + d] = f2bf(bf2f(Q[base + d]) * SM_SCALE);
  }
  float k1 = bf2f(K[base + i]), k2 = bf2f(K[base + 16 + i]);
  K[base + i] = f2bf(k1 * c - k2 * sn);
  K[base + 16 + i] = f2bf(k2 * c + k1 * sn);
}

// ---------------- flash attention (QBLK=256, 8 waves x 32 q-rows) -------
// Q pre-scaled by SM_SCALE. Fast paths: mask loop only for diagonal tiles;
// T13 defer-max (THR=8) skips max-update + O/l rescale when no row grew.
__global__ __launch_bounds__(512) void attn_kernel(const unsigned short* __restrict__ Qb,
                                                   const unsigned short* __restrict__ Kb,
                                                   const unsigned short* __restrict__ Vg,
                                                   unsigned short* __restrict__ Ob) {
  __shared__ __align__(16) unsigned short Klds[64][104];  // D padded 80->96
  __shared__ __align__(16) unsigned short Vt[80][72];     // V^T tile [d][k]
  __shared__ __align__(16) unsigned short Plds[8][32][72];
  const int tid = threadIdx.x;
  const int lane = tid & 63, w = tid >> 6;
  const int lr = lane & 15, lg = lane >> 4;
  const int koff = lg * 8;
  const int qt = blockIdx.x, bh = blockIdx.y;
  const int h = bh & 31;
  const int base = bh * (SEQ * DH);   // Q,K: [B][H][S][D]
  const int vbase = bh * (DH * SEQ);  // V:   [B][H][D][S]

  for (int e = tid; e < 64 * 16; e += 512) Klds[e >> 4][80 + (e & 15)] = 0;

  const int rowbase = qt * 256 + w * 32;
  bf16x8 qf[2][3];
#pragma unroll
  for (int hh = 0; hh < 2; ++hh)
#pragma unroll
    for (int c = 0; c < 3; ++c) {
      const int d = c * 32 + koff;
      if (d < DH)
        qf[hh][c] =
            *(const bf16x8*)(Qb + base + (rowbase + hh * 16 + lr) * DH + d);
      else
        qf[hh][c] = (bf16x8)(__bf16)0.0f;
    }

  float m[2][4], l[2][4];
  f32x4 of[2][5];
#pragma unroll
  for (int hh = 0; hh < 2; ++hh) {
#pragma unroll
    for (int r = 0; r < 4; ++r) {
      m[hh][r] = -3.0e38f;
      l[hh][r] = 0.0f;
    }
#pragma unroll
    for (int d = 0; d < 5; ++d) of[hh][d] = (f32x4)0.0f;
  }

  const int ke0r = tid / 10, ke0c = (tid - (tid / 10) * 10) * 8;
  const int ke1 = tid + 512;
  const int ke1r = ke1 / 10, ke1c = (ke1 - (ke1 / 10) * 10) * 8;
  const int ve0d = tid >> 3, ve0c = (tid & 7) * 8;
  const int ve1d = (tid + 512) >> 3, ve1c = ((tid + 512) & 7) * 8;

  bf16x8 kreg0, kreg1, vreg0, vreg1;
  kreg0 = *(const bf16x8*)(Kb + base + ke0r * DH + ke0c);
  if (tid < 128) kreg1 = *(const bf16x8*)(Kb + base + ke1r * DH + ke1c);
  vreg0 = *(const bf16x8*)(Vg + vbase + ve0d * SEQ + ve0c);
  if (tid < 128) vreg1 = *(const bf16x8*)(Vg + vbase + ve1d * SEQ + ve1c);

  const int ktmax = 4 * qt + 3;
  for (int kt = 0; kt <= ktmax; ++kt) {
    __syncthreads();
    *(bf16x8*)&Klds[ke0r][ke0c] = kreg0;
    if (tid < 128) *(bf16x8*)&Klds[ke1r][ke1c] = kreg1;
    *(bf16x8*)&Vt[ve0d][ve0c] = vreg0;
    if (tid < 128) *(bf16x8*)&Vt[ve1d][ve1c] = vreg1;
    __syncthreads();

    if (kt < ktmax) {  // T14: issue next tile's loads; land during compute
      const int nb = (kt + 1) * 64;
      kreg0 = *(const bf16x8*)(Kb + base + (nb + ke0r) * DH + ke0c);
      if (tid < 128) kreg1 = *(const bf16x8*)(Kb + base + (nb + ke1r) * DH + ke1c);
      vreg0 = *(const bf16x8*)(Vg + vbase + ve0d * SEQ + nb + ve0c);
      if (tid < 128) vreg1 = *(const bf16x8*)(Vg + vbase + ve1d * SEQ + nb + ve1c);
    }

    if (kt * 64 > rowbase + 31) continue;          // fully masked for wave
    const bool fullvis = (kt * 64 + 63 <= rowbase);  // no masking needed

    f32x4 sc[2][4];
#pragma unroll
    for (int hh = 0; hh < 2; ++hh)
#pragma unroll
      for (int cf = 0; cf < 4; ++cf) sc[hh][cf] = (f32x4)0.0f;
#pragma unroll
    for (int c = 0; c < 3; ++c) {
#pragma unroll
      for (int cf = 0; cf < 4; ++cf) {
        bf16x8 kb = *(const bf16x8*)&Klds[cf * 16 + lr][c * 32 + koff];
        sc[0][cf] = __builtin_amdgcn_mfma_f32_16x16x32_bf16(qf[0][c], kb, sc[0][cf], 0, 0, 0);
        sc[1][cf] = __builtin_amdgcn_mfma_f32_16x16x32_bf16(qf[1][c], kb, sc[1][cf], 0, 0, 0);
      }
    }

#pragma unroll
    for (int hh = 0; hh < 2; ++hh) {
      if (!fullvis) {
        const int rowg = rowbase + hh * 16 + lg * 4;
#pragma unroll
        for (int cf = 0; cf < 4; ++cf) {
          const int colg = kt * 64 + cf * 16 + lr;
#pragma unroll
          for (int r = 0; r < 4; ++r)
            if (colg > rowg + r) sc[hh][cf][r] = -1.0e30f;
        }
      }
      float mx[4];
#pragma unroll
      for (int r = 0; r < 4; ++r) {
        float v = fmaxf(fmaxf(sc[hh][0][r], sc[hh][1][r]),
                        fmaxf(sc[hh][2][r], sc[hh][3][r]));
#pragma unroll
        for (int off = 1; off < 16; off <<= 1) v = fmaxf(v, __shfl_xor(v, off, 64));
        mx[r] = v;
      }
      // T13 defer-max: rescale only if some row grew by > 8
      bool need = false;
#pragma unroll
      for (int r = 0; r < 4; ++r) need |= (mx[r] > m[hh][r] + 8.0f);
      if (__ballot(need)) {
        float al[4];
#pragma unroll
        for (int r = 0; r < 4; ++r) {
          const float mn = fmaxf(m[hh][r], mx[r]);
          al[r] = __expf(m[hh][r] - mn);
          m[hh][r] = mn;
        }
#pragma unroll
        for (int d = 0; d < 5; ++d)
#pragma unroll
          for (int r = 0; r < 4; ++r) of[hh][d][r] *= al[r];
#pragma unroll
        for (int r = 0; r < 4; ++r) l[hh][r] *= al[r];
      }
      float ls[4] = {0.f, 0.f, 0.f, 0.f};
#pragma unroll
      for (int cf = 0; cf < 4; ++cf)
#pragma unroll
        for (int r = 0; r < 4; ++r) {
          const float p = __expf(sc[hh][cf][r] - m[hh][r]);
          sc[hh][cf][r] = p;
          ls[r] += p;
        }
#pragma unroll
      for (int r = 0; r < 4; ++r) {
        float sv = ls[r];
#pragma unroll
        for (int off = 1; off < 16; off <<= 1) sv += __shfl_xor(sv, off, 64);
        l[hh][r] += sv;
      }
#pragma unroll
      for (int cf = 0; cf < 4; ++cf)
#pragma unroll
        for (int r = 0; r < 4; ++r)
          Plds[w][hh * 16 + lg * 4 + r][cf * 16 + lr] = f2bf(sc[hh][cf][r]);
    }

#pragma unroll
    for (int kc = 0; kc < 2; ++kc) {
      bf16x8 pa0 = *(const bf16x8*)&Plds[w][lr][kc * 32 + koff];
      bf16x8 pa1 = *(const bf16x8*)&Plds[w][16 + lr][kc * 32 + koff];
#pragma unroll
      for (int d = 0; d < 5; ++d) {
        bf16x8 vb = *(const bf16x8*)&Vt[d * 16 + lr][kc * 32 + koff];
        of[0][d] = __builtin_amdgcn_mfma_f32_16x16x32_bf16(pa0, vb, of[0][d], 0, 0, 0);
        of[1][d] = __builtin_amdgcn_mfma_f32_16x16x32_bf16(pa1, vb, of[1][d], 0, 0, 0);
      }
    }
  }

#pragma unroll
  for (int hh = 0; hh < 2; ++hh) {
    const int t = (bh >> 5) * SEQ + rowbase + hh * 16 + lg * 4;
#pragma unroll
    for (int r = 0; r < 4; ++r) {
      const float rl = 1.0f / l[hh][r];
#pragma unroll
      for (int d = 0; d < 5; ++d)
        Ob[(t + r) * HID + h * DH + d * 16 + lr] = f2bf(of[hh][d][r] * rl);
    }
  }
}

// ---------------- launch ----------------
extern "C" void kernel_launch(void* const* d_in, const int* in_sizes, int n_in,
                              void* d_out, int out_size, void* d_ws, size_t ws_size,
                              hipStream_t stream) {
  const float* hs = (const float*)d_in[0];
  const float* cosb = (const float*)d_in[1];
  const float* sinb = (const float*)d_in[2];
  const float* w_qkv = (const float*)d_in[3];
  const float* b_qkv = (const float*)d_in[4];
  const float* w_dense = (const float*)d_in[5];
  const float* b_dense = (const float*)d_in[6];
  float* out = (float*)d_out;
  char* ws = (char*)d_ws;

  unsigned short* hsb = (unsigned short*)(ws + 0);         // 21.0 MB
  unsigned short* aob = (unsigned short*)(ws + 0);         // alias (attn out)
  unsigned short* wqb = (unsigned short*)(ws + 20971520);  // 39.3 MB
  unsigned short* wdb = (unsigned short*)(ws + 20971520);  // alias
  unsigned short* Qb = (unsigned short*)(ws + 60293120);   // 21.0 MB
  unsigned short* Kb = (unsigned short*)(ws + 81264640);   // 21.0 MB
  unsigned short* Vb = (unsigned short*)(ws + 102236160);  // 21.0 MB ([B][H][D][S])

  cvt_kernel<<<2048, 256, 0, stream>>>(hs, hsb, (NT * HID) / 4);
  cvt_kernel<<<2048, 256, 0, stream>>>(w_qkv, wqb, (NQKV * HID) / 4);
  gemm8p_kernel<0><<<dim3(NQKV / 256, NT / 256), 512, 0, stream>>>(
      hsb, wqb, b_qkv, Qb, Kb, Vb, nullptr, NT, NQKV, HID);
  cvt_kernel<<<2048, 256, 0, stream>>>(w_dense, wdb, (HID * HID) / 4);
  rope_kernel<<<(NB * NH * SEQ * 16) / 256, 256, 0, stream>>>(Qb, Kb, cosb, sinb);
  attn_kernel<<<dim3(SEQ / 256, NB * NH), 512, 0, stream>>>(Qb, Kb, Vb, aob);
  gemm8p_kernel<1><<<dim3(HID / 256, NT / 256), 512, 0, stream>>>(
      aob, wdb, b_dense, nullptr, nullptr, nullptr, out, NT, HID, HID);
}

// Round 12
// 359.995 us; speedup vs baseline: 5.1360x; 1.1072x over previous
//
#include <hip/hip_runtime.h>

typedef __attribute__((ext_vector_type(8))) __bf16 bf16x8;
typedef __attribute__((ext_vector_type(4))) float f32x4;

#define NH 32
#define DH 80
#define SEQ 1024
#define NB 4
#define NT 4096
#define HID 2560
#define NQKV 7680
#define SM_SCALE 0.11180339887498948f

static __device__ __forceinline__ unsigned short f2bf(float f) {
  unsigned u = __builtin_bit_cast(unsigned, f);
  u += 0x7fffu + ((u >> 16) & 1u);
  return (unsigned short)(u >> 16);
}
static __device__ __forceinline__ float bf2f(unsigned short s) {
  unsigned u = (unsigned)s << 16;
  return __builtin_bit_cast(float, u);
}

typedef __attribute__((address_space(1))) const unsigned int as1_uint;
typedef __attribute__((address_space(3))) unsigned int as3_uint;
static __device__ __forceinline__ void gload16(const void* g, void* l) {
  __builtin_amdgcn_global_load_lds((as1_uint*)g, (as3_uint*)l, 16, 0, 0);
}

// ---------------- fp32 -> bf16 convert (vectorized) ----------------
__global__ __launch_bounds__(256) void cvt_kernel(const float* __restrict__ in,
                                                  unsigned short* __restrict__ out,
                                                  int n4) {
  const float4* __restrict__ in4 = (const float4*)in;
  ushort4* __restrict__ out4 = (ushort4*)out;
  for (int i = blockIdx.x * blockDim.x + threadIdx.x; i < n4;
       i += gridDim.x * blockDim.x) {
    float4 v = in4[i];
    ushort4 o;
    o.x = f2bf(v.x);
    o.y = f2bf(v.y);
    o.z = f2bf(v.z);
    o.w = f2bf(v.w);
    out4[i] = o;
  }
}

// ------------- 256x256 8-phase pipelined bf16 GEMM: C = A @ B^T + bias -------
// (unchanged from round 11 — 179us QKV steady, MfmaUtil 38%)
template <int EPI>
__global__ __launch_bounds__(512, 2) void gemm8p_kernel(
    const unsigned short* __restrict__ A, const unsigned short* __restrict__ Bm,
    const float* __restrict__ bias, unsigned short* __restrict__ Cq,
    unsigned short* __restrict__ Ck, unsigned short* __restrict__ Cv,
    float* __restrict__ Cf, int M, int N, int K) {
  __shared__ __align__(16) unsigned short AL[2][2][8192];  // [buf][half][128*64]
  __shared__ __align__(16) unsigned short BL[2][2][8192];
  const int tid = threadIdx.x;
  const int lane = tid & 63, w = tid >> 6;
  const int wm = w >> 2, wn = w & 3;
  const int lr = lane & 15, lg = lane >> 4;
  const int bhh = wn >> 1;
  const int brow = (wn & 1) * 64;

  const int gx = gridDim.x;
  const int nwg = gx * gridDim.y;
  int bid = blockIdx.y * gx + blockIdx.x;
  bid = (bid & 7) * (nwg >> 3) + (bid >> 3);
  const int n0 = (bid % gx) * 256;
  const int m0 = (bid / gx) * 256;

  const unsigned short* asrc[2][2];
  const unsigned short* bsrc[2][2];
#pragma unroll
  for (int h = 0; h < 2; ++h)
#pragma unroll
    for (int j = 0; j < 2; ++j) {
      const int off = j * 8192 + tid * 16;
      const int u = off ^ (((off >> 7) & 7) << 4);
      const int row = u >> 7, col = (u & 127) >> 1;
      asrc[h][j] = A + (size_t)(m0 + h * 128 + row) * K + col;
      bsrc[h][j] = Bm + (size_t)(n0 + h * 128 + row) * K + col;
    }

  const int NK = K >> 6, NIT = NK >> 1;

#define SA(buf, h, kt)                                                     \
  do {                                                                     \
    gload16(asrc[h][0] + (size_t)(kt) * 64,                                \
            (char*)&AL[buf][h][0] + w * 1024);                             \
    gload16(asrc[h][1] + (size_t)(kt) * 64,                                \
            (char*)&AL[buf][h][0] + 8192 + w * 1024);                      \
  } while (0)
#define SB(buf, h, kt)                                                     \
  do {                                                                     \
    gload16(bsrc[h][0] + (size_t)(kt) * 64,                                \
            (char*)&BL[buf][h][0] + w * 1024);                             \
    gload16(bsrc[h][1] + (size_t)(kt) * 64,                                \
            (char*)&BL[buf][h][0] + 8192 + w * 1024);                      \
  } while (0)
#define FA(buf, lrow, ks)                                                  \
  (*(const bf16x8*)((const char*)&AL[buf][wm][0] +                         \
                    (((lrow) * 128 + (ks) * 64 + lg * 16) ^                \
                     (((lrow) & 7) << 4))))
#define FB(buf, lrow, ks)                                                  \
  (*(const bf16x8*)((const char*)&BL[buf][bhh][0] +                        \
                    (((lrow) * 128 + (ks) * 64 + lg * 16) ^                \
                     (((lrow) & 7) << 4))))
#define PH_MFMA(AIDX, NBASE, BREG)                                         \
  __builtin_amdgcn_s_barrier();                                            \
  __builtin_amdgcn_s_setprio(1);                                           \
  _Pragma("unroll") for (int mf = 0; mf < 4; ++mf)                         \
      _Pragma("unroll") for (int nf = 0; nf < 2; ++nf) {                   \
    acc[AIDX + mf][NBASE + nf] = __builtin_amdgcn_mfma_f32_16x16x32_bf16(  \
        af[mf * 2 + 0], BREG[nf * 2 + 0], acc[AIDX + mf][NBASE + nf], 0, 0, 0); \
    acc[AIDX + mf][NBASE + nf] = __builtin_amdgcn_mfma_f32_16x16x32_bf16(  \
        af[mf * 2 + 1], BREG[nf * 2 + 1], acc[AIDX + mf][NBASE + nf], 0, 0, 0); \
  }                                                                        \
  __builtin_amdgcn_s_setprio(0);

  f32x4 acc[8][4];
#pragma unroll
  for (int i = 0; i < 8; ++i)
#pragma unroll
    for (int j = 0; j < 4; ++j) acc[i][j] = (f32x4)0.0f;

  SB(0, 0, 0); SB(0, 1, 0); SA(0, 0, 0); SA(0, 1, 0);
  SB(1, 0, 1); SB(1, 1, 1); SA(1, 0, 1); SA(1, 1, 1);
  asm volatile("s_waitcnt vmcnt(8)" ::: "memory");
  __builtin_amdgcn_s_barrier();

  bf16x8 af[8], bl[4], bhf[4];

  for (int i = 0; i < NIT; ++i) {
    const int t2 = 2 * i + 2, t3 = 2 * i + 3;
    const bool pf = (i + 1) < NIT;

#pragma unroll
    for (int mf = 0; mf < 4; ++mf) {
      af[mf * 2 + 0] = FA(0, mf * 16 + lr, 0);
      af[mf * 2 + 1] = FA(0, mf * 16 + lr, 1);
    }
#pragma unroll
    for (int nf = 0; nf < 2; ++nf) {
      bl[nf * 2 + 0] = FB(0, brow + nf * 16 + lr, 0);
      bl[nf * 2 + 1] = FB(0, brow + nf * 16 + lr, 1);
    }
    PH_MFMA(0, 0, bl)
    __builtin_amdgcn_s_barrier();
#pragma unroll
    for (int nf = 0; nf < 2; ++nf) {
      bhf[nf * 2 + 0] = FB(0, brow + (nf + 2) * 16 + lr, 0);
      bhf[nf * 2 + 1] = FB(0, brow + (nf + 2) * 16 + lr, 1);
    }
    PH_MFMA(0, 2, bhf)
    __builtin_amdgcn_s_barrier();
#pragma unroll
    for (int mf = 0; mf < 4; ++mf) {
      af[mf * 2 + 0] = FA(0, 64 + mf * 16 + lr, 0);
      af[mf * 2 + 1] = FA(0, 64 + mf * 16 + lr, 1);
    }
    if (pf) { SB(0, 0, t2); SB(0, 1, t2); }
    PH_MFMA(4, 0, bl)
    __builtin_amdgcn_s_barrier();
    if (pf) { SA(0, 0, t2); SA(0, 1, t2); }
    PH_MFMA(4, 2, bhf)
    if (pf)
      asm volatile("s_waitcnt vmcnt(8)" ::: "memory");
    else
      asm volatile("s_waitcnt vmcnt(0)" ::: "memory");
    __builtin_amdgcn_s_barrier();

#pragma unroll
    for (int mf = 0; mf < 4; ++mf) {
      af[mf * 2 + 0] = FA(1, mf * 16 + lr, 0);
      af[mf * 2 + 1] = FA(1, mf * 16 + lr, 1);
    }
#pragma unroll
    for (int nf = 0; nf < 2; ++nf) {
      bl[nf * 2 + 0] = FB(1, brow + nf * 16 + lr, 0);
      bl[nf * 2 + 1] = FB(1, brow + nf * 16 + lr, 1);
    }
    PH_MFMA(0, 0, bl)
    __builtin_amdgcn_s_barrier();
#pragma unroll
    for (int nf = 0; nf < 2; ++nf) {
      bhf[nf * 2 + 0] = FB(1, brow + (nf + 2) * 16 + lr, 0);
      bhf[nf * 2 + 1] = FB(1, brow + (nf + 2) * 16 + lr, 1);
    }
    PH_MFMA(0, 2, bhf)
    __builtin_amdgcn_s_barrier();
#pragma unroll
    for (int mf = 0; mf < 4; ++mf) {
      af[mf * 2 + 0] = FA(1, 64 + mf * 16 + lr, 0);
      af[mf * 2 + 1] = FA(1, 64 + mf * 16 + lr, 1);
    }
    if (pf) { SB(1, 0, t3); SB(1, 1, t3); }
    PH_MFMA(4, 0, bl)
    __builtin_amdgcn_s_barrier();
    if (pf) { SA(1, 0, t3); SA(1, 1, t3); }
    PH_MFMA(4, 2, bhf)
    if (pf) asm volatile("s_waitcnt vmcnt(8)" ::: "memory");
    __builtin_amdgcn_s_barrier();
  }
#undef SA
#undef SB
#undef FA
#undef FB
#undef PH_MFMA

  if (EPI == 0) {
    if (n0 >= 2 * HID) {
      unsigned short* scr = (unsigned short*)&AL[0][0][0] + w * 2176;
      const int bb = (m0 + wm * 128) >> 10;
      const int ssb = (m0 + wm * 128) & 1023;
#pragma unroll
      for (int nf = 0; nf < 4; ++nf) {
        const int col0 = n0 - 2 * HID + wn * 64 + nf * 16;
        const int hh = col0 / DH;
        const int dd0 = col0 - hh * DH;
        const float bv = bias[2 * HID + col0 + lr];
#pragma unroll
        for (int mf = 0; mf < 8; ++mf) {
          ushort4 p;
          p.x = f2bf(acc[mf][nf][0] + bv);
          p.y = f2bf(acc[mf][nf][1] + bv);
          p.z = f2bf(acc[mf][nf][2] + bv);
          p.w = f2bf(acc[mf][nf][3] + bv);
          *(ushort4*)&scr[lr * 136 + mf * 16 + lg * 4] = p;
        }
#pragma unroll
        for (int it = 0; it < 4; ++it) {
          const int dd = (lane >> 4) + it * 4;
          const int sl = (lane & 15) * 8;
          bf16x8 v = *(const bf16x8*)&scr[dd * 136 + sl];
          *(bf16x8*)(Cv + ((size_t)(bb * NH + hh) * DH + dd0 + dd) * SEQ + ssb + sl) = v;
        }
        asm volatile("s_waitcnt lgkmcnt(0)" ::: "memory");
      }
    } else {
#pragma unroll
      for (int nf = 0; nf < 4; ++nf) {
        const int col = n0 + wn * 64 + nf * 16 + lr;
        const int sec = col >= HID ? 1 : 0;
        const int rem = col - sec * HID;
        const int hh = rem / DH;
        const int dd = rem - hh * DH;
        unsigned short* dst = sec ? Ck : Cq;
        const float bv = bias[col];
#pragma unroll
        for (int mf = 0; mf < 8; ++mf) {
#pragma unroll
          for (int r = 0; r < 4; ++r) {
            const int tr = m0 + wm * 128 + mf * 16 + lg * 4 + r;
            const int bb2 = tr >> 10, ss = tr & 1023;
            dst[((size_t)(bb2 * NH + hh) * SEQ + ss) * DH + dd] =
                f2bf(acc[mf][nf][r] + bv);
          }
        }
      }
    }
  } else {
#pragma unroll
    for (int nf = 0; nf < 4; ++nf) {
      const int col = n0 + wn * 64 + nf * 16 + lr;
      const float bv = bias[col];
#pragma unroll
      for (int mf = 0; mf < 8; ++mf)
#pragma unroll
        for (int r = 0; r < 4; ++r) {
          const int row = m0 + wm * 128 + mf * 16 + lg * 4 + r;
          Cf[row * N + col] = acc[mf][nf][r] + bv;
        }
    }
  }
}

// ------- in-place partial rotary on Q,K; Q additionally pre-scaled -------
__global__ __launch_bounds__(256) void rope_kernel(unsigned short* __restrict__ Q,
                                                   unsigned short* __restrict__ K,
                                                   const float* __restrict__ cosb,
                                                   const float* __restrict__ sinb) {
  const int idx = blockIdx.x * 256 + threadIdx.x;  // B*H*S*16
  const int i = idx & 15;
  const int s = (idx >> 4) & 1023;
  const int bh = idx >> 14;
  const int b = bh >> 5;
  const int t = b * SEQ + s;
  const float c = cosb[t * 16 + i];
  const float sn = sinb[t * 16 + i];
  const int base = (bh * SEQ + s) * DH;
  float q1 = bf2f(Q[base + i]), q2 = bf2f(Q[base + 16 + i]);
  Q[base + i] = f2bf((q1 * c - q2 * sn) * SM_SCALE);
  Q[base + 16 + i] = f2bf((q2 * c + q1 * sn) * SM_SCALE);
#pragma unroll
  for (int j = 0; j < 3; ++j) {
    const int d = 32 + j * 16 + i;
    Q[base + d] = f2bf(bf2f(Q[base + d]) * SM_SCALE);
  }
  float k1 = bf2f(K[base + i]), k2 = bf2f(K[base + 16 + i]);
  K[base + i] = f2bf(k1 * c - k2 * sn);
  K[base + 16 + i] = f2bf(k2 * c + k1 * sn);
}

// ------- flash attention (QBLK=256, 8 waves x 32 q-rows, causal-paired) -----
// grid: (2, B*H). Block x processes q-tiles {x, 3-x} sequentially -> every
// block does exactly 20 tile-units (balanced; 256 blocks = 1/CU, no tail).
// Q pre-scaled by SM_SCALE. Mask loop only on diagonal tiles; T13 defer-max;
// T14 async-stage (next tile's K/V loads issued during compute).
__global__ __launch_bounds__(512) void attn_kernel(const unsigned short* __restrict__ Qb,
                                                   const unsigned short* __restrict__ Kb,
                                                   const unsigned short* __restrict__ Vg,
                                                   unsigned short* __restrict__ Ob) {
  __shared__ __align__(16) unsigned short Klds[64][104];  // D padded 80->96
  __shared__ __align__(16) unsigned short Vt[80][72];     // V^T tile [d][k]
  __shared__ __align__(16) unsigned short Plds[8][32][72];
  const int tid = threadIdx.x;
  const int lane = tid & 63, w = tid >> 6;
  const int lr = lane & 15, lg = lane >> 4;
  const int koff = lg * 8;
  const int bh = blockIdx.y;
  const int h = bh & 31;
  const int base = bh * (SEQ * DH);   // Q,K: [B][H][S][D]
  const int vbase = bh * (DH * SEQ);  // V:   [B][H][D][S]

  for (int e = tid; e < 64 * 16; e += 512) Klds[e >> 4][80 + (e & 15)] = 0;

  // staging coords (fixed per thread)
  const int ke0r = tid / 10, ke0c = (tid - (tid / 10) * 10) * 8;
  const int ke1 = tid + 512;
  const int ke1r = ke1 / 10, ke1c = (ke1 - (ke1 / 10) * 10) * 8;
  const int ve0d = tid >> 3, ve0c = (tid & 7) * 8;
  const int ve1d = (tid + 512) >> 3, ve1c = ((tid + 512) & 7) * 8;

  const int qts[2] = {(int)blockIdx.x, 3 - (int)blockIdx.x};

  for (int sub = 0; sub < 2; ++sub) {
    const int qt = qts[sub];
    const int rowbase = qt * 256 + w * 32;

    bf16x8 qf[2][3];
#pragma unroll
    for (int hh = 0; hh < 2; ++hh)
#pragma unroll
      for (int c = 0; c < 3; ++c) {
        const int d = c * 32 + koff;
        if (d < DH)
          qf[hh][c] =
              *(const bf16x8*)(Qb + base + (rowbase + hh * 16 + lr) * DH + d);
        else
          qf[hh][c] = (bf16x8)(__bf16)0.0f;
      }

    float m[2][4], l[2][4];
    f32x4 of[2][5];
#pragma unroll
    for (int hh = 0; hh < 2; ++hh) {
#pragma unroll
      for (int r = 0; r < 4; ++r) {
        m[hh][r] = -3.0e38f;
        l[hh][r] = 0.0f;
      }
#pragma unroll
      for (int d = 0; d < 5; ++d) of[hh][d] = (f32x4)0.0f;
    }

    bf16x8 kreg0, kreg1, vreg0, vreg1;
    kreg0 = *(const bf16x8*)(Kb + base + ke0r * DH + ke0c);
    if (tid < 128) kreg1 = *(const bf16x8*)(Kb + base + ke1r * DH + ke1c);
    vreg0 = *(const bf16x8*)(Vg + vbase + ve0d * SEQ + ve0c);
    if (tid < 128) vreg1 = *(const bf16x8*)(Vg + vbase + ve1d * SEQ + ve1c);

    const int ktmax = 4 * qt + 3;
    for (int kt = 0; kt <= ktmax; ++kt) {
      __syncthreads();  // prior tile's (and prior sub's) LDS reads complete
      *(bf16x8*)&Klds[ke0r][ke0c] = kreg0;
      if (tid < 128) *(bf16x8*)&Klds[ke1r][ke1c] = kreg1;
      *(bf16x8*)&Vt[ve0d][ve0c] = vreg0;
      if (tid < 128) *(bf16x8*)&Vt[ve1d][ve1c] = vreg1;
      __syncthreads();  // tile visible

      if (kt < ktmax) {  // T14: issue next tile's loads; land during compute
        const int nb = (kt + 1) * 64;
        kreg0 = *(const bf16x8*)(Kb + base + (nb + ke0r) * DH + ke0c);
        if (tid < 128) kreg1 = *(const bf16x8*)(Kb + base + (nb + ke1r) * DH + ke1c);
        vreg0 = *(const bf16x8*)(Vg + vbase + ve0d * SEQ + nb + ve0c);
        if (tid < 128) vreg1 = *(const bf16x8*)(Vg + vbase + ve1d * SEQ + nb + ve1c);
      }

      if (kt * 64 > rowbase + 31) continue;            // fully masked for wave
      const bool fullvis = (kt * 64 + 63 <= rowbase);  // no masking needed

      f32x4 sc[2][4];
#pragma unroll
      for (int hh = 0; hh < 2; ++hh)
#pragma unroll
        for (int cf = 0; cf < 4; ++cf) sc[hh][cf] = (f32x4)0.0f;
#pragma unroll
      for (int c = 0; c < 3; ++c) {
#pragma unroll
        for (int cf = 0; cf < 4; ++cf) {
          bf16x8 kb = *(const bf16x8*)&Klds[cf * 16 + lr][c * 32 + koff];
          sc[0][cf] = __builtin_amdgcn_mfma_f32_16x16x32_bf16(qf[0][c], kb, sc[0][cf], 0, 0, 0);
          sc[1][cf] = __builtin_amdgcn_mfma_f32_16x16x32_bf16(qf[1][c], kb, sc[1][cf], 0, 0, 0);
        }
      }

#pragma unroll
      for (int hh = 0; hh < 2; ++hh) {
        if (!fullvis) {
          const int rowg = rowbase + hh * 16 + lg * 4;
#pragma unroll
          for (int cf = 0; cf < 4; ++cf) {
            const int colg = kt * 64 + cf * 16 + lr;
#pragma unroll
            for (int r = 0; r < 4; ++r)
              if (colg > rowg + r) sc[hh][cf][r] = -1.0e30f;
          }
        }
        float mx[4];
#pragma unroll
        for (int r = 0; r < 4; ++r) {
          float v = fmaxf(fmaxf(sc[hh][0][r], sc[hh][1][r]),
                          fmaxf(sc[hh][2][r], sc[hh][3][r]));
#pragma unroll
          for (int off = 1; off < 16; off <<= 1) v = fmaxf(v, __shfl_xor(v, off, 64));
          mx[r] = v;
        }
        bool need = false;  // T13 defer-max
#pragma unroll
        for (int r = 0; r < 4; ++r) need |= (mx[r] > m[hh][r] + 8.0f);
        if (__ballot(need)) {
          float al[4];
#pragma unroll
          for (int r = 0; r < 4; ++r) {
            const float mn = fmaxf(m[hh][r], mx[r]);
            al[r] = __expf(m[hh][r] - mn);
            m[hh][r] = mn;
          }
#pragma unroll
          for (int d = 0; d < 5; ++d)
#pragma unroll
            for (int r = 0; r < 4; ++r) of[hh][d][r] *= al[r];
#pragma unroll
          for (int r = 0; r < 4; ++r) l[hh][r] *= al[r];
        }
        float ls[4] = {0.f, 0.f, 0.f, 0.f};
#pragma unroll
        for (int cf = 0; cf < 4; ++cf)
#pragma unroll
          for (int r = 0; r < 4; ++r) {
            const float p = __expf(sc[hh][cf][r] - m[hh][r]);
            sc[hh][cf][r] = p;
            ls[r] += p;
          }
#pragma unroll
        for (int r = 0; r < 4; ++r) {
          float sv = ls[r];
#pragma unroll
          for (int off = 1; off < 16; off <<= 1) sv += __shfl_xor(sv, off, 64);
          l[hh][r] += sv;
        }
#pragma unroll
        for (int cf = 0; cf < 4; ++cf)
#pragma unroll
          for (int r = 0; r < 4; ++r)
            Plds[w][hh * 16 + lg * 4 + r][cf * 16 + lr] = f2bf(sc[hh][cf][r]);
      }

#pragma unroll
      for (int kc = 0; kc < 2; ++kc) {
        bf16x8 pa0 = *(const bf16x8*)&Plds[w][lr][kc * 32 + koff];
        bf16x8 pa1 = *(const bf16x8*)&Plds[w][16 + lr][kc * 32 + koff];
#pragma unroll
        for (int d = 0; d < 5; ++d) {
          bf16x8 vb = *(const bf16x8*)&Vt[d * 16 + lr][kc * 32 + koff];
          of[0][d] = __builtin_amdgcn_mfma_f32_16x16x32_bf16(pa0, vb, of[0][d], 0, 0, 0);
          of[1][d] = __builtin_amdgcn_mfma_f32_16x16x32_bf16(pa1, vb, of[1][d], 0, 0, 0);
        }
      }
    }

#pragma unroll
    for (int hh = 0; hh < 2; ++hh) {
      const int t = (bh >> 5) * SEQ + rowbase + hh * 16 + lg * 4;
#pragma unroll
      for (int r = 0; r < 4; ++r) {
        const float rl = 1.0f / l[hh][r];
#pragma unroll
        for (int d = 0; d < 5; ++d)
          Ob[(t + r) * HID + h * DH + d * 16 + lr] = f2bf(of[hh][d][r] * rl);
      }
    }
  }
}

// ---------------- launch ----------------
extern "C" void kernel_launch(void* const* d_in, const int* in_sizes, int n_in,
                              void* d_out, int out_size, void* d_ws, size_t ws_size,
                              hipStream_t stream) {
  const float* hs = (const float*)d_in[0];
  const float* cosb = (const float*)d_in[1];
  const float* sinb = (const float*)d_in[2];
  const float* w_qkv = (const float*)d_in[3];
  const float* b_qkv = (const float*)d_in[4];
  const float* w_dense = (const float*)d_in[5];
  const float* b_dense = (const float*)d_in[6];
  float* out = (float*)d_out;
  char* ws = (char*)d_ws;

  unsigned short* hsb = (unsigned short*)(ws + 0);         // 21.0 MB
  unsigned short* aob = (unsigned short*)(ws + 0);         // alias (attn out)
  unsigned short* wqb = (unsigned short*)(ws + 20971520);  // 39.3 MB
  unsigned short* wdb = (unsigned short*)(ws + 20971520);  // alias
  unsigned short* Qb = (unsigned short*)(ws + 60293120);   // 21.0 MB
  unsigned short* Kb = (unsigned short*)(ws + 81264640);   // 21.0 MB
  unsigned short* Vb = (unsigned short*)(ws + 102236160);  // 21.0 MB ([B][H][D][S])

  cvt_kernel<<<2048, 256, 0, stream>>>(hs, hsb, (NT * HID) / 4);
  cvt_kernel<<<2048, 256, 0, stream>>>(w_qkv, wqb, (NQKV * HID) / 4);
  gemm8p_kernel<0><<<dim3(NQKV / 256, NT / 256), 512, 0, stream>>>(
      hsb, wqb, b_qkv, Qb, Kb, Vb, nullptr, NT, NQKV, HID);
  cvt_kernel<<<2048, 256, 0, stream>>>(w_dense, wdb, (HID * HID) / 4);
  rope_kernel<<<(NB * NH * SEQ * 16) / 256, 256, 0, stream>>>(Qb, Kb, cosb, sinb);
  attn_kernel<<<dim3(2, NB * NH), 512, 0, stream>>>(Qb, Kb, Vb, aob);
  gemm8p_kernel<1><<<dim3(HID / 256, NT / 256), 512, 0, stream>>>(
      aob, wdb, b_dense, nullptr, nullptr, nullptr, out, NT, HID, HID);
}